// Round 6
// baseline (267.103 us; speedup 1.0000x reference)
//
#include <hip/hip_runtime.h>
#include <cstdint>
#include <cmath>

#define DEV __device__ __forceinline__

constexpr int SEL = 20;
constexpr int NSTEP2 = 10, NSTEP3 = 22, NSTEPS = 32;
constexpr int L2 = SEL + 1;   // 21 bits, group2
constexpr int L3 = SEL;       // 20 bits, group3
constexpr int H = 4;
constexpr int P = 8;          // Chebyshev probes

// ---- ws layout (float indices) ----
constexpr int OFF_T      = 0;                               // T[2][22][P] = 352
constexpr int OFF_SUMS   = OFF_T + 2 * 22 * P;              // 352
constexpr int SUMS_STRIDE = 96;                             // [0]=Se [1]=Sw [2..5]=Sws [6..9]=Swh [10+h*21+d]=GW1
constexpr int OFF_PCHAIN = OFF_SUMS + NSTEPS * SUMS_STRIDE; // pchain[33]
constexpr int OFF_KEYB   = OFF_PCHAIN + 40;                 // keybase[32][4]
constexpr int OFF_CT     = OFF_KEYB + 128;                  // int c_t[32]
constexpr int OFF_CB     = OFF_CT + 32;                     // uint chunkbits[32]
constexpr int OFF_NEED   = OFF_CB + 32;                     // uint neededmask[2]
constexpr int WS_FLOATS  = OFF_NEED + 8;

// runtime-indexed copies (kb only)
__constant__ float CHEB_P[P] = {0.9903926402f, 0.9157348062f, 0.7777851165f, 0.5975451610f,
                                0.4024548390f, 0.2222148835f, 0.0842651938f, 0.0096073598f};
__constant__ float CHEB_W[P] = {0.1950903220f, -0.5555702330f, 0.8314696123f, -0.9807852804f,
                                0.9807852804f, -0.8314696123f, 0.5555702330f, -0.1950903220f};
// compile-time immediates (ka)
constexpr float CHEB_PC[P] = {0.9903926402f, 0.9157348062f, 0.7777851165f, 0.5975451610f,
                              0.4024548390f, 0.2222148835f, 0.0842651938f, 0.0096073598f};

struct Binom { unsigned v[22][22]; };
constexpr Binom make_binom() {
  Binom b{};
  for (int n = 0; n < 22; n++) {
    b.v[n][0] = 1;
    for (int k = 1; k < 22; k++)
      b.v[n][k] = (k > n) ? 0u : (k == n ? 1u : b.v[n - 1][k - 1] + b.v[n - 1][k]);
  }
  return b;
}
constexpr Binom BN_H = make_binom();              // host/compile-time
__device__ constexpr Binom BN = make_binom();     // device runtime table

DEV float fast_tanh(float x) {
  float e = exp2f(x * 2.8853900817779268f);  // e^(2x)
  return 1.0f - 2.0f * __builtin_amdgcn_rcpf(e + 1.0f);
}
DEV float fast_exp(float x) { return exp2f(x * 1.4426950408889634f); }

DEV unsigned gosper(unsigned cmb) {
  unsigned u = cmb & (~cmb + 1u);
  unsigned v = cmb + u;
  return v | ((cmb ^ v) >> (1 + __ffs(u)));
}

// colex unrank: rank r within class (L choose c) -> bit pattern
DEV unsigned unrank_lds(const unsigned* sBN, int L, int c, unsigned r) {
  unsigned cmb = 0; int kk = c;
  for (int bb = L - 1; bb >= 0 && kk > 0; bb--) {
    unsigned cnt = sBN[bb * 22 + kk];
    if (r >= cnt) { cmb |= 1u << bb; r -= cnt; kk--; }
  }
  return cmb;
}

constexpr unsigned cdiv_u(unsigned a, unsigned b) { return (a + b - 1) / b; }

DEV float wsum64(float v) {
  for (int m = 1; m < 64; m <<= 1) v += __shfl_xor(v, m);
  return v;
}

// =================== Kernel Z: init / decode chunks ===================
__global__ void kz(const float* p0, const float* sel,
                   const float* W1_2, const float* b1_2,
                   const float* W1_3, const float* b1_3, float* ws) {
  int t = threadIdx.x;
  for (int i = t; i < WS_FLOATS; i += blockDim.x) ws[i] = 0.0f;
  __syncthreads();
  if (t < NSTEPS) {
    int g = (t < NSTEP2) ? 0 : 1;
    int L = g ? L3 : L2;
    const float* sbase = sel + (g ? (NSTEP2 * L2 + (t - NSTEP2) * L3) : t * L2);
    unsigned cb = 0; int c = 0;
    for (int d = 0; d < L; d++)
      if (sbase[d] > 0.5f) { cb |= 1u << d; c++; }
    ((int*)ws)[OFF_CT + t] = c;
    ((unsigned*)ws)[OFF_CB + t] = cb;
    atomicOr(&((unsigned*)ws)[OFF_NEED + g], 1u << c);
    const float* W1 = g ? W1_3 : W1_2;
    const float* b1 = g ? b1_3 : b1_2;
    for (int h = 0; h < H; h++) {
      float s = b1[h];
      for (int d = 0; d < L; d++)
        if ((cb >> d) & 1) s += W1[h * (L + 1) + 1 + d];
      ws[OFF_KEYB + t * 4 + h] = s;
    }
    if (t == 0) ws[OFF_PCHAIN] = p0[0];
  }
}

// =================== Kernel A: per-class tabulation of T[g][c][j] ===================
constexpr int KA_CPT = 32;
constexpr int KA_RPB = 256 * KA_CPT; // 8192 ranks per block

struct KaOff { int off2[23]; int off3[22]; int total2; int total; };
constexpr KaOff make_kaoff() {
  KaOff o{};
  int cum = 0;
  for (int c = 0; c <= 21; c++) { o.off2[c] = cum; cum += (int)cdiv_u(BN_H.v[21][c], KA_RPB); }
  o.off2[22] = cum; o.total2 = cum;
  int cum3 = 0;
  for (int c = 0; c <= 20; c++) { o.off3[c] = cum3; cum3 += (int)cdiv_u(BN_H.v[20][c], KA_RPB); }
  o.off3[21] = cum3;
  o.total = cum + cum3;
  return o;
}
constexpr KaOff KAOFF = make_kaoff();

template<int LL>
DEV void tab_setup(const float* W1, const float* b1,
                   float4* tab0, float4* tab1, float4* tab2) {
  int tx = threadIdx.x;
  for (int i = tx; i < 384; i += 256) {
    int which = i >> 7, e = i & 127;
    int lo = which * 7; int nb = (which < 2) ? 7 : (LL - 14);
    float4 v; float* vp = (float*)&v;
    for (int h = 0; h < 4; h++) {
      float s = (which == 0) ? b1[h] : 0.0f;
      for (int j = 0; j < nb; j++)
        if ((e >> j) & 1) s += W1[h * (LL + 1) + 1 + lo + j];
      vp[h] = s;
    }
    if (which == 0) tab0[e] = v; else if (which == 1) tab1[e] = v; else tab2[e] = v;
  }
}

// one Chebyshev-probe half (4 probes) — keeps live accumulators at 4
template<int LL, int J0>
DEV void ka_pass(int g, int c, unsigned C, unsigned r0, int nI,
                 float a0, float a1, float a2, float a3,
                 float w0, float w1, float w2, float w3, float b2s,
                 const unsigned* sBN, const float4* tab0, const float4* tab1, const float4* tab2,
                 float* ws) {
  int tx = threadIdx.x;
  unsigned cmb = (nI > 0) ? unrank_lds(sBN, LL, c, r0) : 0u;
  float acc0 = 0, acc1 = 0, acc2 = 0, acc3 = 0;
#pragma unroll 1
  for (int k = 0; k < nI; k++) {
    unsigned n = cmb;
    float4 v0 = tab0[n & 127], v1 = tab1[(n >> 7) & 127], v2 = tab2[(n >> 14) & 127];
    float base0 = v0.x + v1.x + v2.x, base1 = v0.y + v1.y + v2.y;
    float base2 = v0.z + v1.z + v2.z, base3 = v0.w + v1.w + v2.w;
#define PROBE(i) { \
    float t0 = fast_tanh(fmaf(CHEB_PC[J0 + i], a0, base0)); \
    float t1 = fast_tanh(fmaf(CHEB_PC[J0 + i], a1, base1)); \
    float t2 = fast_tanh(fmaf(CHEB_PC[J0 + i], a2, base2)); \
    float t3 = fast_tanh(fmaf(CHEB_PC[J0 + i], a3, base3)); \
    float outv = b2s + w0 * t0 + w1 * t1 + w2 * t2 + w3 * t3; \
    acc##i += fast_exp(outv); }
    PROBE(0) PROBE(1) PROBE(2) PROBE(3)
#undef PROBE
    cmb = gosper(cmb);
  }
#define FLUSH(i) { \
    float v = wsum64(acc##i); \
    if ((tx & 63) == 0 && v != 0.0f) atomicAdd(&ws[OFF_T + g * 22 * P + c * P + J0 + i], v); }
  FLUSH(0) FLUSH(1) FLUSH(2) FLUSH(3)
#undef FLUSH
}

template<int LL>
DEV void ka_work(int g, int c, int sub,
                 const float* W1, const float* b1, const float* W2, const float* b2,
                 float* ws, unsigned* sBN, float4* tab0, float4* tab1, float4* tab2) {
  int tx = threadIdx.x;
  const unsigned* bnf = &BN.v[0][0];
  for (int i = tx; i < 484; i += 256) sBN[i] = bnf[i];
  tab_setup<LL>(W1, b1, tab0, tab1, tab2);
  __syncthreads();
  float a0 = W1[0], a1 = W1[LL + 1], a2 = W1[2 * (LL + 1)], a3 = W1[3 * (LL + 1)];
  float w0 = W2[0], w1 = W2[1], w2 = W2[2], w3 = W2[3];
  float b2s = b2[0];
  unsigned C = BN.v[LL][c];
  unsigned r0 = (unsigned)sub * KA_RPB + (unsigned)tx * KA_CPT;
  int nI = (int)C - (int)r0;
  if (nI > KA_CPT) nI = KA_CPT;
  ka_pass<LL, 0>(g, c, C, r0, nI, a0, a1, a2, a3, w0, w1, w2, w3, b2s, sBN, tab0, tab1, tab2, ws);
  ka_pass<LL, 4>(g, c, C, r0, nI, a0, a1, a2, a3, w0, w1, w2, w3, b2s, sBN, tab0, tab1, tab2, ws);
}

__global__ __launch_bounds__(256) void ka(
    const float* W1_2, const float* b1_2, const float* W2_2, const float* b2_2,
    const float* W1_3, const float* b1_3, const float* W2_3, const float* b2_3,
    float* ws) {
  __shared__ unsigned sBN[484];
  __shared__ float4 tab0[128], tab1[128], tab2[128];
  int b = blockIdx.x;
  int g, c = 0, sub;
  if (b < KAOFF.total2) {
    g = 0;
#pragma unroll
    for (int cc = 1; cc <= 21; cc++) if (b >= KAOFF.off2[cc]) c = cc;
    sub = b - KAOFF.off2[c];
  } else {
    g = 1; int b3 = b - KAOFF.total2;
#pragma unroll
    for (int cc = 1; cc <= 20; cc++) if (b3 >= KAOFF.off3[cc]) c = cc;
    sub = b3 - KAOFF.off3[c];
  }
  unsigned need = ((const unsigned*)ws)[OFF_NEED + g];
  if (!((need >> c) & 1)) return;
  if (g == 0) ka_work<21>(0, c, sub, W1_2, b1_2, W2_2, b2_2, ws, sBN, tab0, tab1, tab2);
  else        ka_work<20>(1, c, sub, W1_3, b1_3, W2_3, b2_3, ws, sBN, tab0, tab1, tab2);
}

// =================== Kernel B: sequential prob chain via Chebyshev interp ===================
__global__ void kb(const float* p0in,
                   const float* W1_2, const float* b1_2, const float* W2_2, const float* b2_2,
                   const float* W1_3, const float* b1_3, const float* W2_3, const float* b2_3,
                   float* ws, float* out) {
  if (threadIdx.x != 0) return;
  float p = p0in[0];
  out[0] = p;
  ws[OFF_PCHAIN] = p;
  for (int tt = 0; tt < NSTEPS; tt++) {
    int g = (tt < NSTEP2) ? 0 : 1;
    int L = g ? L3 : L2;
    const float* W1 = g ? W1_3 : W1_2;
    const float* W2 = g ? W2_3 : W2_2;
    float b2s = (g ? b2_3 : b2_2)[0];
    int c = ((const int*)ws)[OFF_CT + tt];
    float outk = b2s;
    for (int h = 0; h < H; h++) {
      float hk = fast_tanh(ws[OFF_KEYB + tt * 4 + h] + p * W1[h * (L + 1)]);
      outk += W2[h] * hk;
    }
    const float* T = &ws[OFF_T + g * 22 * P + c * P];
    float num = 0.0f, den = 0.0f, Sehit = 0.0f;
    bool hit = false;
#pragma unroll
    for (int j = 0; j < P; j++) {
      float d = p - CHEB_P[j];
      if (fabsf(d) < 1e-8f) { hit = true; Sehit = T[j]; }
      else { float q = CHEB_W[j] / d; num += q * T[j]; den += q; }
    }
    float Se = hit ? Sehit : (num / den);
    p = fast_exp(outk) / Se;
    ws[OFF_PCHAIN + 1 + tt] = p;
    out[1 + tt] = p;
  }
}

// =================== Kernel C: exact per-class 94-sum reductions, 3 passes ===================
constexpr int KC_CPT = 32;
constexpr int KC_RPB = 256 * KC_CPT; // 8192
constexpr int KC_B2 = (int)cdiv_u(BN_H.v[21][10], KC_RPB); // 44
constexpr int KC_B3 = (int)cdiv_u(BN_H.v[20][10], KC_RPB); // 23
constexpr int KC_BLOCKS = NSTEP2 * KC_B2 + NSTEP3 * KC_B3;

// one pass: CORE sums (optional) + gradient bit-sums for d in [DLO, DLO+NDS)
template<int LL, int DLO, int NDS, bool CORE>
DEV void kc_pass(int c, unsigned C, unsigned r0, int nI,
                 float pa0, float pa1, float pa2, float pa3,
                 float w0, float w1, float w2, float w3, float b2s,
                 const unsigned* sBN, const float4* tab0, const float4* tab1, const float4* tab2,
                 float* S) {
  int tx = threadIdx.x;
  unsigned cmb = (nI > 0) ? unrank_lds(sBN, LL, c, r0) : 0u;
  float aE = 0, aW = 0, aQ0 = 0, aQ1 = 0, aQ2 = 0, aQ3 = 0;
  float aWH0 = 0, aWH1 = 0, aWH2 = 0, aWH3 = 0;
  float g0_0 = 0, g0_1 = 0, g0_2 = 0, g0_3 = 0;
  float g1_0 = 0, g1_1 = 0, g1_2 = 0, g1_3 = 0;
  float g2_0 = 0, g2_1 = 0, g2_2 = 0, g2_3 = 0;
  float g3_0 = 0, g3_1 = 0, g3_2 = 0, g3_3 = 0;
  float g4_0 = 0, g4_1 = 0, g4_2 = 0, g4_3 = 0;
  float g5_0 = 0, g5_1 = 0, g5_2 = 0, g5_3 = 0;
  float g6_0 = 0, g6_1 = 0, g6_2 = 0, g6_3 = 0;
  float g7_0 = 0, g7_1 = 0, g7_2 = 0, g7_3 = 0;
#pragma unroll 1
  for (int k = 0; k < nI; k++) {
    unsigned n = cmb;
    float4 v0 = tab0[n & 127], v1 = tab1[(n >> 7) & 127], v2 = tab2[(n >> 14) & 127];
    float t0 = fast_tanh(v0.x + v1.x + v2.x + pa0);
    float t1 = fast_tanh(v0.y + v1.y + v2.y + pa1);
    float t2 = fast_tanh(v0.z + v1.z + v2.z + pa2);
    float t3 = fast_tanh(v0.w + v1.w + v2.w + pa3);
    float outv = b2s + w0 * t0 + w1 * t1 + w2 * t2 + w3 * t3;
    float q0 = outv * (1.0f - t0 * t0) * w0;
    float q1 = outv * (1.0f - t1 * t1) * w1;
    float q2 = outv * (1.0f - t2 * t2) * w2;
    float q3 = outv * (1.0f - t3 * t3) * w3;
    if constexpr (CORE) {
      aE += fast_exp(outv); aW += outv;
      aQ0 += q0; aQ1 += q1; aQ2 += q2; aQ3 += q3;
      aWH0 = fmaf(outv, t0, aWH0); aWH1 = fmaf(outv, t1, aWH1);
      aWH2 = fmaf(outv, t2, aWH2); aWH3 = fmaf(outv, t3, aWH3);
    }
#define GU(i) if constexpr (i < NDS) { float bd = (float)((n >> (DLO + i)) & 1u); \
    g##i##_0 = fmaf(bd, q0, g##i##_0); g##i##_1 = fmaf(bd, q1, g##i##_1); \
    g##i##_2 = fmaf(bd, q2, g##i##_2); g##i##_3 = fmaf(bd, q3, g##i##_3); }
    GU(0) GU(1) GU(2) GU(3) GU(4) GU(5) GU(6) GU(7)
#undef GU
    cmb = gosper(cmb);
  }
  int lane = tx & 63;
  float r;
  if constexpr (CORE) {
    r = wsum64(aE);   if (lane == 0 && r != 0.0f) atomicAdd(&S[0], r);
    r = wsum64(aW);   if (lane == 0 && r != 0.0f) atomicAdd(&S[1], r);
    r = wsum64(aQ0);  if (lane == 0 && r != 0.0f) atomicAdd(&S[2], r);
    r = wsum64(aQ1);  if (lane == 0 && r != 0.0f) atomicAdd(&S[3], r);
    r = wsum64(aQ2);  if (lane == 0 && r != 0.0f) atomicAdd(&S[4], r);
    r = wsum64(aQ3);  if (lane == 0 && r != 0.0f) atomicAdd(&S[5], r);
    r = wsum64(aWH0); if (lane == 0 && r != 0.0f) atomicAdd(&S[6], r);
    r = wsum64(aWH1); if (lane == 0 && r != 0.0f) atomicAdd(&S[7], r);
    r = wsum64(aWH2); if (lane == 0 && r != 0.0f) atomicAdd(&S[8], r);
    r = wsum64(aWH3); if (lane == 0 && r != 0.0f) atomicAdd(&S[9], r);
  }
#define GF(i) if constexpr (i < NDS) { \
    r = wsum64(g##i##_0); if (lane == 0 && r != 0.0f) atomicAdd(&S[10 + 0 * 21 + DLO + i], r); \
    r = wsum64(g##i##_1); if (lane == 0 && r != 0.0f) atomicAdd(&S[10 + 1 * 21 + DLO + i], r); \
    r = wsum64(g##i##_2); if (lane == 0 && r != 0.0f) atomicAdd(&S[10 + 2 * 21 + DLO + i], r); \
    r = wsum64(g##i##_3); if (lane == 0 && r != 0.0f) atomicAdd(&S[10 + 3 * 21 + DLO + i], r); }
  GF(0) GF(1) GF(2) GF(3) GF(4) GF(5) GF(6) GF(7)
#undef GF
}

template<int LL>
DEV void kc_work(int t, int sub,
                 const float* W1, const float* b1, const float* W2, const float* b2,
                 float* ws, unsigned* sBN, float4* tab0, float4* tab1, float4* tab2) {
  int tx = threadIdx.x;
  int c = ((const int*)ws)[OFF_CT + t];
  unsigned C = BN.v[LL][c];
  unsigned rank0 = (unsigned)sub * KC_RPB;
  if (rank0 >= C) return;   // block-uniform early exit (before any barrier)
  const unsigned* bnf = &BN.v[0][0];
  for (int i = tx; i < 484; i += 256) sBN[i] = bnf[i];
  tab_setup<LL>(W1, b1, tab0, tab1, tab2);
  __syncthreads();
  float p = ws[OFF_PCHAIN + t];
  float pa0 = p * W1[0], pa1 = p * W1[LL + 1], pa2 = p * W1[2 * (LL + 1)], pa3 = p * W1[3 * (LL + 1)];
  float w0 = W2[0], w1 = W2[1], w2 = W2[2], w3 = W2[3];
  float b2s = b2[0];
  unsigned r0 = rank0 + (unsigned)tx * KC_CPT;
  int nI = (int)C - (int)r0;
  if (nI > KC_CPT) nI = KC_CPT;
  float* S = &ws[OFF_SUMS + t * SUMS_STRIDE];
  kc_pass<LL, 0, 5, true >(c, C, r0, nI, pa0, pa1, pa2, pa3, w0, w1, w2, w3, b2s, sBN, tab0, tab1, tab2, S);
  kc_pass<LL, 5, 8, false>(c, C, r0, nI, pa0, pa1, pa2, pa3, w0, w1, w2, w3, b2s, sBN, tab0, tab1, tab2, S);
  kc_pass<LL, 13, LL - 13, false>(c, C, r0, nI, pa0, pa1, pa2, pa3, w0, w1, w2, w3, b2s, sBN, tab0, tab1, tab2, S);
}

__global__ __launch_bounds__(256) void kc(
    const float* W1_2, const float* b1_2, const float* W2_2, const float* b2_2,
    const float* W1_3, const float* b1_3, const float* W2_3, const float* b2_3,
    float* ws) {
  __shared__ unsigned sBN[484];
  __shared__ float4 tab0[128], tab1[128], tab2[128];
  int b = blockIdx.x;
  if (b < NSTEP2 * KC_B2) {
    int t = b / KC_B2, sub = b % KC_B2;
    kc_work<21>(t, sub, W1_2, b1_2, W2_2, b2_2, ws, sBN, tab0, tab1, tab2);
  } else {
    int bb = b - NSTEP2 * KC_B2;
    int t = NSTEP2 + bb / KC_B3, sub = bb % KC_B3;
    kc_work<20>(t, sub, W1_3, b1_3, W2_3, b2_3, ws, sBN, tab0, tab1, tab2);
  }
}

// =================== Kernel D: finalize gradient outputs ===================
__global__ void kd(const float* W1_2, const float* b1_2, const float* W2_2, const float* b2_2,
                   const float* W1_3, const float* b1_3, const float* W2_3, const float* b2_3,
                   const float* ws, float* out) {
  __shared__ float sk_s[NSTEPS][4], hk_s[NSTEPS][4], pp_s[NSTEPS], s0i_s[NSTEPS];
  int tx = threadIdx.x;
  if (tx < NSTEPS) {
    int t = tx; int g = (t < NSTEP2) ? 0 : 1; int L = g ? L3 : L2;
    const float* W1 = g ? W1_3 : W1_2;
    const float* W2 = g ? W2_3 : W2_2;
    float p = ws[OFF_PCHAIN + t];
    pp_s[t] = p;
    s0i_s[t] = 1.0f / ws[OFF_SUMS + t * SUMS_STRIDE + 0];
    for (int h = 0; h < 4; h++) {
      float hk = fast_tanh(ws[OFF_KEYB + t * 4 + h] + p * W1[h * (L + 1)]);
      hk_s[t][h] = hk;
      sk_s[t][h] = (1.0f - hk * hk) * W2[h];
    }
  }
  __syncthreads();
  const unsigned* cbp = (const unsigned*)ws;
  for (int o = 33 + tx; o < 223; o += blockDim.x) {
    float val = 0.0f;
    if (o < 130) {                           // ---- group2 grads ----
      if (o < 121) {                         // W1_2 grad [4][22]
        int e = o - 33; int h = e / 22, d = e % 22;
        for (int t = 0; t < NSTEP2; t++) {
          float xk = (d == 0) ? pp_s[t] : (float)((cbp[OFF_CB + t] >> (d - 1)) & 1);
          float gs = (d == 0) ? pp_s[t] * ws[OFF_SUMS + t * SUMS_STRIDE + 2 + h]
                              : ws[OFF_SUMS + t * SUMS_STRIDE + 10 + h * 21 + (d - 1)];
          val += sk_s[t][h] * xk - gs * s0i_s[t];
        }
      } else if (o < 125) { int h = o - 121;
        for (int t = 0; t < NSTEP2; t++) val += sk_s[t][h] - ws[OFF_SUMS + t * SUMS_STRIDE + 2 + h] * s0i_s[t];
      } else if (o < 129) { int h = o - 125;
        for (int t = 0; t < NSTEP2; t++) val += hk_s[t][h] - ws[OFF_SUMS + t * SUMS_STRIDE + 6 + h] * s0i_s[t];
      } else {
        for (int t = 0; t < NSTEP2; t++) val += 1.0f - ws[OFF_SUMS + t * SUMS_STRIDE + 1] * s0i_s[t];
      }
    } else {                                 // ---- group3 grads ----
      if (o < 214) {                         // W1_3 grad [4][21]
        int e = o - 130; int h = e / 21, d = e % 21;
        for (int t = NSTEP2; t < NSTEPS; t++) {
          float xk = (d == 0) ? pp_s[t] : (float)((cbp[OFF_CB + t] >> (d - 1)) & 1);
          float gs = (d == 0) ? pp_s[t] * ws[OFF_SUMS + t * SUMS_STRIDE + 2 + h]
                              : ws[OFF_SUMS + t * SUMS_STRIDE + 10 + h * 21 + (d - 1)];
          val += sk_s[t][h] * xk - gs * s0i_s[t];
        }
      } else if (o < 218) { int h = o - 214;
        for (int t = NSTEP2; t < NSTEPS; t++) val += sk_s[t][h] - ws[OFF_SUMS + t * SUMS_STRIDE + 2 + h] * s0i_s[t];
      } else if (o < 222) { int h = o - 218;
        for (int t = NSTEP2; t < NSTEPS; t++) val += hk_s[t][h] - ws[OFF_SUMS + t * SUMS_STRIDE + 6 + h] * s0i_s[t];
      } else {
        for (int t = NSTEP2; t < NSTEPS; t++) val += 1.0f - ws[OFF_SUMS + t * SUMS_STRIDE + 1] * s0i_s[t];
      }
    }
    out[o] = val;
  }
}

extern "C" void kernel_launch(void* const* d_in, const int* in_sizes, int n_in,
                              void* d_out, int out_size, void* d_ws, size_t ws_size,
                              hipStream_t stream) {
  const float* p0   = (const float*)d_in[0];
  const float* sel  = (const float*)d_in[1];
  const float* W1_2 = (const float*)d_in[2]; const float* b1_2 = (const float*)d_in[3];
  const float* W2_2 = (const float*)d_in[4]; const float* b2_2 = (const float*)d_in[5];
  const float* W1_3 = (const float*)d_in[6]; const float* b1_3 = (const float*)d_in[7];
  const float* W2_3 = (const float*)d_in[8]; const float* b2_3 = (const float*)d_in[9];
  float* out = (float*)d_out;
  float* ws  = (float*)d_ws;
  hipLaunchKernelGGL(kz, dim3(1), dim3(256), 0, stream, p0, sel, W1_2, b1_2, W1_3, b1_3, ws);
  hipLaunchKernelGGL(ka, dim3(KAOFF.total), dim3(256), 0, stream,
                     W1_2, b1_2, W2_2, b2_2, W1_3, b1_3, W2_3, b2_3, ws);
  hipLaunchKernelGGL(kb, dim3(1), dim3(64), 0, stream, p0,
                     W1_2, b1_2, W2_2, b2_2, W1_3, b1_3, W2_3, b2_3, ws, out);
  hipLaunchKernelGGL(kc, dim3(KC_BLOCKS), dim3(256), 0, stream,
                     W1_2, b1_2, W2_2, b2_2, W1_3, b1_3, W2_3, b2_3, ws);
  hipLaunchKernelGGL(kd, dim3(1), dim3(256), 0, stream,
                     W1_2, b1_2, W2_2, b2_2, W1_3, b1_3, W2_3, b2_3, ws, out);
}

// Round 7
// 220.354 us; speedup vs baseline: 1.2122x; 1.2122x over previous
//
#include <hip/hip_runtime.h>
#include <cstdint>
#include <cmath>

#define DEV __device__ __forceinline__

constexpr int SEL = 20;
constexpr int NSTEP2 = 10, NSTEP3 = 22, NSTEPS = 32;
constexpr int L2 = SEL + 1;   // 21 bits, group2
constexpr int L3 = SEL;       // 20 bits, group3
constexpr int H = 4;
constexpr int P = 8;          // Chebyshev probes

// ---- ws layout (float indices) ----
constexpr int OFF_T      = 0;                               // T[2][22][P] = 352
constexpr int OFF_SUMS   = OFF_T + 2 * 22 * P;              // 352
constexpr int SUMS_STRIDE = 96;                             // [0]=Se [1]=Sw [2..5]=Sws [6..9]=Swh [10+h*21+d]=GW1
constexpr int OFF_PCHAIN = OFF_SUMS + NSTEPS * SUMS_STRIDE; // pchain[33]
constexpr int OFF_KEYB   = OFF_PCHAIN + 40;                 // keybase[32][4]
constexpr int OFF_CT     = OFF_KEYB + 128;                  // int c_t[32]
constexpr int OFF_CB     = OFF_CT + 32;                     // uint chunkbits[32]
constexpr int OFF_NEED   = OFF_CB + 32;                     // uint neededmask[2]
constexpr int WS_FLOATS  = OFF_NEED + 8;

// runtime-indexed copies (kb only)
__constant__ float CHEB_P[P] = {0.9903926402f, 0.9157348062f, 0.7777851165f, 0.5975451610f,
                                0.4024548390f, 0.2222148835f, 0.0842651938f, 0.0096073598f};
__constant__ float CHEB_W[P] = {0.1950903220f, -0.5555702330f, 0.8314696123f, -0.9807852804f,
                                0.9807852804f, -0.8314696123f, 0.5555702330f, -0.1950903220f};
// compile-time immediates (ka)
constexpr float CHEB_PC[P] = {0.9903926402f, 0.9157348062f, 0.7777851165f, 0.5975451610f,
                              0.4024548390f, 0.2222148835f, 0.0842651938f, 0.0096073598f};

struct Binom { unsigned v[22][22]; };
constexpr Binom make_binom() {
  Binom b{};
  for (int n = 0; n < 22; n++) {
    b.v[n][0] = 1;
    for (int k = 1; k < 22; k++)
      b.v[n][k] = (k > n) ? 0u : (k == n ? 1u : b.v[n - 1][k - 1] + b.v[n - 1][k]);
  }
  return b;
}
constexpr Binom BN_H = make_binom();              // host/compile-time
__device__ constexpr Binom BN = make_binom();     // device runtime table

DEV float fast_tanh(float x) {
  float e = exp2f(x * 2.8853900817779268f);  // e^(2x)
  return 1.0f - 2.0f * __builtin_amdgcn_rcpf(e + 1.0f);
}
DEV float fast_exp(float x) { return exp2f(x * 1.4426950408889634f); }

// native fp32 atomic (global_atomic_add_f32) — avoids hipcc's default CAS loop
DEV void gatomic(float* p, float v) { unsafeAtomicAdd(p, v); }

DEV unsigned gosper(unsigned cmb) {
  unsigned u = cmb & (~cmb + 1u);
  unsigned v = cmb + u;
  return v | ((cmb ^ v) >> (1 + __ffs(u)));
}

// colex unrank: rank r within class (L choose c) -> bit pattern
DEV unsigned unrank_lds(const unsigned* sBN, int L, int c, unsigned r) {
  unsigned cmb = 0; int kk = c;
  for (int bb = L - 1; bb >= 0 && kk > 0; bb--) {
    unsigned cnt = sBN[bb * 22 + kk];
    if (r >= cnt) { cmb |= 1u << bb; r -= cnt; kk--; }
  }
  return cmb;
}

constexpr unsigned cdiv_u(unsigned a, unsigned b) { return (a + b - 1) / b; }

DEV float wsum64(float v) {
  for (int m = 1; m < 64; m <<= 1) v += __shfl_xor(v, m);
  return v;
}

// =================== Kernel Z: init / decode chunks ===================
__global__ void kz(const float* p0, const float* sel,
                   const float* W1_2, const float* b1_2,
                   const float* W1_3, const float* b1_3, float* ws) {
  int t = threadIdx.x;
  for (int i = t; i < WS_FLOATS; i += blockDim.x) ws[i] = 0.0f;
  __syncthreads();
  if (t < NSTEPS) {
    int g = (t < NSTEP2) ? 0 : 1;
    int L = g ? L3 : L2;
    const float* sbase = sel + (g ? (NSTEP2 * L2 + (t - NSTEP2) * L3) : t * L2);
    unsigned cb = 0; int c = 0;
    for (int d = 0; d < L; d++)
      if (sbase[d] > 0.5f) { cb |= 1u << d; c++; }
    ((int*)ws)[OFF_CT + t] = c;
    ((unsigned*)ws)[OFF_CB + t] = cb;
    atomicOr(&((unsigned*)ws)[OFF_NEED + g], 1u << c);
    const float* W1 = g ? W1_3 : W1_2;
    const float* b1 = g ? b1_3 : b1_2;
    for (int h = 0; h < H; h++) {
      float s = b1[h];
      for (int d = 0; d < L; d++)
        if ((cb >> d) & 1) s += W1[h * (L + 1) + 1 + d];
      ws[OFF_KEYB + t * 4 + h] = s;
    }
    if (t == 0) ws[OFF_PCHAIN] = p0[0];
  }
}

// =================== Kernel A: per-class tabulation of T[g][c][j] ===================
constexpr int KA_CPT = 8;
constexpr int KA_RPB = 256 * KA_CPT; // 2048 ranks per block

struct KaOff { int off2[23]; int off3[22]; int total2; int total; };
constexpr KaOff make_kaoff() {
  KaOff o{};
  int cum = 0;
  for (int c = 0; c <= 21; c++) { o.off2[c] = cum; cum += (int)cdiv_u(BN_H.v[21][c], KA_RPB); }
  o.off2[22] = cum; o.total2 = cum;
  int cum3 = 0;
  for (int c = 0; c <= 20; c++) { o.off3[c] = cum3; cum3 += (int)cdiv_u(BN_H.v[20][c], KA_RPB); }
  o.off3[21] = cum3;
  o.total = cum + cum3;
  return o;
}
constexpr KaOff KAOFF = make_kaoff();

template<int LL>
DEV void tab_setup(const float* W1, const float* b1,
                   float4* tab0, float4* tab1, float4* tab2) {
  int tx = threadIdx.x;
  for (int i = tx; i < 384; i += 256) {
    int which = i >> 7, e = i & 127;
    int lo = which * 7; int nb = (which < 2) ? 7 : (LL - 14);
    float4 v; float* vp = (float*)&v;
    for (int h = 0; h < 4; h++) {
      float s = (which == 0) ? b1[h] : 0.0f;
      for (int j = 0; j < nb; j++)
        if ((e >> j) & 1) s += W1[h * (LL + 1) + 1 + lo + j];
      vp[h] = s;
    }
    if (which == 0) tab0[e] = v; else if (which == 1) tab1[e] = v; else tab2[e] = v;
  }
}

// one Chebyshev-probe half (4 probes) — keeps live accumulators at 4
template<int LL, int J0>
DEV void ka_pass(int c, unsigned r0, int nI,
                 float a0, float a1, float a2, float a3,
                 float w0, float w1, float w2, float w3, float b2s,
                 const unsigned* sBN, const float4* tab0, const float4* tab1, const float4* tab2,
                 float* sT) {
  int tx = threadIdx.x;
  unsigned cmb = (nI > 0) ? unrank_lds(sBN, LL, c, r0) : 0u;
  float acc0 = 0, acc1 = 0, acc2 = 0, acc3 = 0;
#pragma unroll 1
  for (int k = 0; k < nI; k++) {
    unsigned n = cmb;
    float4 v0 = tab0[n & 127], v1 = tab1[(n >> 7) & 127], v2 = tab2[(n >> 14) & 127];
    float base0 = v0.x + v1.x + v2.x, base1 = v0.y + v1.y + v2.y;
    float base2 = v0.z + v1.z + v2.z, base3 = v0.w + v1.w + v2.w;
#define PROBE(i) { \
    float t0 = fast_tanh(fmaf(CHEB_PC[J0 + i], a0, base0)); \
    float t1 = fast_tanh(fmaf(CHEB_PC[J0 + i], a1, base1)); \
    float t2 = fast_tanh(fmaf(CHEB_PC[J0 + i], a2, base2)); \
    float t3 = fast_tanh(fmaf(CHEB_PC[J0 + i], a3, base3)); \
    float outv = b2s + w0 * t0 + w1 * t1 + w2 * t2 + w3 * t3; \
    acc##i += fast_exp(outv); }
    PROBE(0) PROBE(1) PROBE(2) PROBE(3)
#undef PROBE
    cmb = gosper(cmb);
  }
#define FLUSH(i) { \
    float v = wsum64(acc##i); \
    if ((tx & 63) == 0 && v != 0.0f) atomicAdd(&sT[J0 + i], v); }
  FLUSH(0) FLUSH(1) FLUSH(2) FLUSH(3)
#undef FLUSH
}

template<int LL>
DEV void ka_work(int g, int c, int sub,
                 const float* W1, const float* b1, const float* W2, const float* b2,
                 float* ws, unsigned* sBN, float4* tab0, float4* tab1, float4* tab2,
                 float* sT) {
  int tx = threadIdx.x;
  const unsigned* bnf = &BN.v[0][0];
  for (int i = tx; i < 484; i += 256) sBN[i] = bnf[i];
  if (tx < P) sT[tx] = 0.0f;
  tab_setup<LL>(W1, b1, tab0, tab1, tab2);
  __syncthreads();
  float a0 = W1[0], a1 = W1[LL + 1], a2 = W1[2 * (LL + 1)], a3 = W1[3 * (LL + 1)];
  float w0 = W2[0], w1 = W2[1], w2 = W2[2], w3 = W2[3];
  float b2s = b2[0];
  unsigned C = BN.v[LL][c];
  unsigned r0 = (unsigned)sub * KA_RPB + (unsigned)tx * KA_CPT;
  int nI = (int)C - (int)r0;
  if (nI > KA_CPT) nI = KA_CPT;
  ka_pass<LL, 0>(c, r0, nI, a0, a1, a2, a3, w0, w1, w2, w3, b2s, sBN, tab0, tab1, tab2, sT);
  ka_pass<LL, 4>(c, r0, nI, a0, a1, a2, a3, w0, w1, w2, w3, b2s, sBN, tab0, tab1, tab2, sT);
  __syncthreads();
  if (tx < P) {
    float v = sT[tx];
    if (v != 0.0f) gatomic(&ws[OFF_T + g * 22 * P + c * P + tx], v);
  }
}

__global__ __launch_bounds__(256) void ka(
    const float* W1_2, const float* b1_2, const float* W2_2, const float* b2_2,
    const float* W1_3, const float* b1_3, const float* W2_3, const float* b2_3,
    float* ws) {
  __shared__ unsigned sBN[484];
  __shared__ float4 tab0[128], tab1[128], tab2[128];
  __shared__ float sT[P];
  int b = blockIdx.x;
  int g, c = 0, sub;
  if (b < KAOFF.total2) {
    g = 0;
#pragma unroll
    for (int cc = 1; cc <= 21; cc++) if (b >= KAOFF.off2[cc]) c = cc;
    sub = b - KAOFF.off2[c];
  } else {
    g = 1; int b3 = b - KAOFF.total2;
#pragma unroll
    for (int cc = 1; cc <= 20; cc++) if (b3 >= KAOFF.off3[cc]) c = cc;
    sub = b3 - KAOFF.off3[c];
  }
  unsigned need = ((const unsigned*)ws)[OFF_NEED + g];
  if (!((need >> c) & 1)) return;
  if (g == 0) ka_work<21>(0, c, sub, W1_2, b1_2, W2_2, b2_2, ws, sBN, tab0, tab1, tab2, sT);
  else        ka_work<20>(1, c, sub, W1_3, b1_3, W2_3, b2_3, ws, sBN, tab0, tab1, tab2, sT);
}

// =================== Kernel B: sequential prob chain via Chebyshev interp ===================
__global__ void kb(const float* p0in,
                   const float* W1_2, const float* b1_2, const float* W2_2, const float* b2_2,
                   const float* W1_3, const float* b1_3, const float* W2_3, const float* b2_3,
                   float* ws, float* out) {
  if (threadIdx.x != 0) return;
  float p = p0in[0];
  out[0] = p;
  ws[OFF_PCHAIN] = p;
  for (int tt = 0; tt < NSTEPS; tt++) {
    int g = (tt < NSTEP2) ? 0 : 1;
    int L = g ? L3 : L2;
    const float* W1 = g ? W1_3 : W1_2;
    const float* W2 = g ? W2_3 : W2_2;
    float b2s = (g ? b2_3 : b2_2)[0];
    int c = ((const int*)ws)[OFF_CT + tt];
    float outk = b2s;
    for (int h = 0; h < H; h++) {
      float hk = fast_tanh(ws[OFF_KEYB + tt * 4 + h] + p * W1[h * (L + 1)]);
      outk += W2[h] * hk;
    }
    const float* T = &ws[OFF_T + g * 22 * P + c * P];
    float num = 0.0f, den = 0.0f, Sehit = 0.0f;
    bool hit = false;
#pragma unroll
    for (int j = 0; j < P; j++) {
      float d = p - CHEB_P[j];
      if (fabsf(d) < 1e-8f) { hit = true; Sehit = T[j]; }
      else { float q = CHEB_W[j] / d; num += q * T[j]; den += q; }
    }
    float Se = hit ? Sehit : (num / den);
    p = fast_exp(outk) / Se;
    ws[OFF_PCHAIN + 1 + tt] = p;
    out[1 + tt] = p;
  }
}

// =================== Kernel C: exact per-class 94-sum reductions, 3 passes ===================
constexpr int KC_CPT = 16;
constexpr int KC_RPB = 256 * KC_CPT; // 4096
constexpr int KC_B2 = (int)cdiv_u(BN_H.v[21][10], KC_RPB); // 87
constexpr int KC_B3 = (int)cdiv_u(BN_H.v[20][10], KC_RPB); // 46
constexpr int KC_BLOCKS = NSTEP2 * KC_B2 + NSTEP3 * KC_B3;

// one pass: CORE sums (optional) + gradient bit-sums for d in [DLO, DLO+NDS)
template<int LL, int DLO, int NDS, bool CORE>
DEV void kc_pass(int c, unsigned r0, int nI,
                 float pa0, float pa1, float pa2, float pa3,
                 float w0, float w1, float w2, float w3, float b2s,
                 const unsigned* sBN, const float4* tab0, const float4* tab1, const float4* tab2,
                 float* sS) {
  int tx = threadIdx.x;
  unsigned cmb = (nI > 0) ? unrank_lds(sBN, LL, c, r0) : 0u;
  float aE = 0, aW = 0, aQ0 = 0, aQ1 = 0, aQ2 = 0, aQ3 = 0;
  float aWH0 = 0, aWH1 = 0, aWH2 = 0, aWH3 = 0;
  float g0_0 = 0, g0_1 = 0, g0_2 = 0, g0_3 = 0;
  float g1_0 = 0, g1_1 = 0, g1_2 = 0, g1_3 = 0;
  float g2_0 = 0, g2_1 = 0, g2_2 = 0, g2_3 = 0;
  float g3_0 = 0, g3_1 = 0, g3_2 = 0, g3_3 = 0;
  float g4_0 = 0, g4_1 = 0, g4_2 = 0, g4_3 = 0;
  float g5_0 = 0, g5_1 = 0, g5_2 = 0, g5_3 = 0;
  float g6_0 = 0, g6_1 = 0, g6_2 = 0, g6_3 = 0;
  float g7_0 = 0, g7_1 = 0, g7_2 = 0, g7_3 = 0;
#pragma unroll 1
  for (int k = 0; k < nI; k++) {
    unsigned n = cmb;
    float4 v0 = tab0[n & 127], v1 = tab1[(n >> 7) & 127], v2 = tab2[(n >> 14) & 127];
    float t0 = fast_tanh(v0.x + v1.x + v2.x + pa0);
    float t1 = fast_tanh(v0.y + v1.y + v2.y + pa1);
    float t2 = fast_tanh(v0.z + v1.z + v2.z + pa2);
    float t3 = fast_tanh(v0.w + v1.w + v2.w + pa3);
    float outv = b2s + w0 * t0 + w1 * t1 + w2 * t2 + w3 * t3;
    float q0 = outv * (1.0f - t0 * t0) * w0;
    float q1 = outv * (1.0f - t1 * t1) * w1;
    float q2 = outv * (1.0f - t2 * t2) * w2;
    float q3 = outv * (1.0f - t3 * t3) * w3;
    if constexpr (CORE) {
      aE += fast_exp(outv); aW += outv;
      aQ0 += q0; aQ1 += q1; aQ2 += q2; aQ3 += q3;
      aWH0 = fmaf(outv, t0, aWH0); aWH1 = fmaf(outv, t1, aWH1);
      aWH2 = fmaf(outv, t2, aWH2); aWH3 = fmaf(outv, t3, aWH3);
    }
#define GU(i) if constexpr (i < NDS) { float bd = (float)((n >> (DLO + i)) & 1u); \
    g##i##_0 = fmaf(bd, q0, g##i##_0); g##i##_1 = fmaf(bd, q1, g##i##_1); \
    g##i##_2 = fmaf(bd, q2, g##i##_2); g##i##_3 = fmaf(bd, q3, g##i##_3); }
    GU(0) GU(1) GU(2) GU(3) GU(4) GU(5) GU(6) GU(7)
#undef GU
    cmb = gosper(cmb);
  }
  int lane = tx & 63;
  float r;
  if constexpr (CORE) {
    r = wsum64(aE);   if (lane == 0 && r != 0.0f) atomicAdd(&sS[0], r);
    r = wsum64(aW);   if (lane == 0 && r != 0.0f) atomicAdd(&sS[1], r);
    r = wsum64(aQ0);  if (lane == 0 && r != 0.0f) atomicAdd(&sS[2], r);
    r = wsum64(aQ1);  if (lane == 0 && r != 0.0f) atomicAdd(&sS[3], r);
    r = wsum64(aQ2);  if (lane == 0 && r != 0.0f) atomicAdd(&sS[4], r);
    r = wsum64(aQ3);  if (lane == 0 && r != 0.0f) atomicAdd(&sS[5], r);
    r = wsum64(aWH0); if (lane == 0 && r != 0.0f) atomicAdd(&sS[6], r);
    r = wsum64(aWH1); if (lane == 0 && r != 0.0f) atomicAdd(&sS[7], r);
    r = wsum64(aWH2); if (lane == 0 && r != 0.0f) atomicAdd(&sS[8], r);
    r = wsum64(aWH3); if (lane == 0 && r != 0.0f) atomicAdd(&sS[9], r);
  }
#define GF(i) if constexpr (i < NDS) { \
    r = wsum64(g##i##_0); if (lane == 0 && r != 0.0f) atomicAdd(&sS[10 + 0 * 21 + DLO + i], r); \
    r = wsum64(g##i##_1); if (lane == 0 && r != 0.0f) atomicAdd(&sS[10 + 1 * 21 + DLO + i], r); \
    r = wsum64(g##i##_2); if (lane == 0 && r != 0.0f) atomicAdd(&sS[10 + 2 * 21 + DLO + i], r); \
    r = wsum64(g##i##_3); if (lane == 0 && r != 0.0f) atomicAdd(&sS[10 + 3 * 21 + DLO + i], r); }
  GF(0) GF(1) GF(2) GF(3) GF(4) GF(5) GF(6) GF(7)
#undef GF
}

template<int LL>
DEV void kc_work(int t, int sub,
                 const float* W1, const float* b1, const float* W2, const float* b2,
                 float* ws, unsigned* sBN, float4* tab0, float4* tab1, float4* tab2,
                 float* sS) {
  int tx = threadIdx.x;
  int c = ((const int*)ws)[OFF_CT + t];
  unsigned C = BN.v[LL][c];
  unsigned rank0 = (unsigned)sub * KC_RPB;
  if (rank0 >= C) return;   // block-uniform early exit (before any barrier)
  const unsigned* bnf = &BN.v[0][0];
  for (int i = tx; i < 484; i += 256) sBN[i] = bnf[i];
  if (tx < SUMS_STRIDE) sS[tx] = 0.0f;
  tab_setup<LL>(W1, b1, tab0, tab1, tab2);
  __syncthreads();
  float p = ws[OFF_PCHAIN + t];
  float pa0 = p * W1[0], pa1 = p * W1[LL + 1], pa2 = p * W1[2 * (LL + 1)], pa3 = p * W1[3 * (LL + 1)];
  float w0 = W2[0], w1 = W2[1], w2 = W2[2], w3 = W2[3];
  float b2s = b2[0];
  unsigned r0 = rank0 + (unsigned)tx * KC_CPT;
  int nI = (int)C - (int)r0;
  if (nI > KC_CPT) nI = KC_CPT;
  kc_pass<LL, 0, 5, true >(c, r0, nI, pa0, pa1, pa2, pa3, w0, w1, w2, w3, b2s, sBN, tab0, tab1, tab2, sS);
  kc_pass<LL, 5, 8, false>(c, r0, nI, pa0, pa1, pa2, pa3, w0, w1, w2, w3, b2s, sBN, tab0, tab1, tab2, sS);
  kc_pass<LL, 13, LL - 13, false>(c, r0, nI, pa0, pa1, pa2, pa3, w0, w1, w2, w3, b2s, sBN, tab0, tab1, tab2, sS);
  __syncthreads();
  if (tx < SUMS_STRIDE) {
    float v = sS[tx];
    if (v != 0.0f) gatomic(&ws[OFF_SUMS + t * SUMS_STRIDE + tx], v);
  }
}

__global__ __launch_bounds__(256) void kc(
    const float* W1_2, const float* b1_2, const float* W2_2, const float* b2_2,
    const float* W1_3, const float* b1_3, const float* W2_3, const float* b2_3,
    float* ws) {
  __shared__ unsigned sBN[484];
  __shared__ float4 tab0[128], tab1[128], tab2[128];
  __shared__ float sS[SUMS_STRIDE];
  int b = blockIdx.x;
  if (b < NSTEP2 * KC_B2) {
    int t = b / KC_B2, sub = b % KC_B2;
    kc_work<21>(t, sub, W1_2, b1_2, W2_2, b2_2, ws, sBN, tab0, tab1, tab2, sS);
  } else {
    int bb = b - NSTEP2 * KC_B2;
    int t = NSTEP2 + bb / KC_B3, sub = bb % KC_B3;
    kc_work<20>(t, sub, W1_3, b1_3, W2_3, b2_3, ws, sBN, tab0, tab1, tab2, sS);
  }
}

// =================== Kernel D: finalize gradient outputs ===================
__global__ void kd(const float* W1_2, const float* b1_2, const float* W2_2, const float* b2_2,
                   const float* W1_3, const float* b1_3, const float* W2_3, const float* b2_3,
                   const float* ws, float* out) {
  __shared__ float sk_s[NSTEPS][4], hk_s[NSTEPS][4], pp_s[NSTEPS], s0i_s[NSTEPS];
  int tx = threadIdx.x;
  if (tx < NSTEPS) {
    int t = tx; int g = (t < NSTEP2) ? 0 : 1; int L = g ? L3 : L2;
    const float* W1 = g ? W1_3 : W1_2;
    const float* W2 = g ? W2_3 : W2_2;
    float p = ws[OFF_PCHAIN + t];
    pp_s[t] = p;
    s0i_s[t] = 1.0f / ws[OFF_SUMS + t * SUMS_STRIDE + 0];
    for (int h = 0; h < 4; h++) {
      float hk = fast_tanh(ws[OFF_KEYB + t * 4 + h] + p * W1[h * (L + 1)]);
      hk_s[t][h] = hk;
      sk_s[t][h] = (1.0f - hk * hk) * W2[h];
    }
  }
  __syncthreads();
  const unsigned* cbp = (const unsigned*)ws;
  for (int o = 33 + tx; o < 223; o += blockDim.x) {
    float val = 0.0f;
    if (o < 130) {                           // ---- group2 grads ----
      if (o < 121) {                         // W1_2 grad [4][22]
        int e = o - 33; int h = e / 22, d = e % 22;
        for (int t = 0; t < NSTEP2; t++) {
          float xk = (d == 0) ? pp_s[t] : (float)((cbp[OFF_CB + t] >> (d - 1)) & 1);
          float gs = (d == 0) ? pp_s[t] * ws[OFF_SUMS + t * SUMS_STRIDE + 2 + h]
                              : ws[OFF_SUMS + t * SUMS_STRIDE + 10 + h * 21 + (d - 1)];
          val += sk_s[t][h] * xk - gs * s0i_s[t];
        }
      } else if (o < 125) { int h = o - 121;
        for (int t = 0; t < NSTEP2; t++) val += sk_s[t][h] - ws[OFF_SUMS + t * SUMS_STRIDE + 2 + h] * s0i_s[t];
      } else if (o < 129) { int h = o - 125;
        for (int t = 0; t < NSTEP2; t++) val += hk_s[t][h] - ws[OFF_SUMS + t * SUMS_STRIDE + 6 + h] * s0i_s[t];
      } else {
        for (int t = 0; t < NSTEP2; t++) val += 1.0f - ws[OFF_SUMS + t * SUMS_STRIDE + 1] * s0i_s[t];
      }
    } else {                                 // ---- group3 grads ----
      if (o < 214) {                         // W1_3 grad [4][21]
        int e = o - 130; int h = e / 21, d = e % 21;
        for (int t = NSTEP2; t < NSTEPS; t++) {
          float xk = (d == 0) ? pp_s[t] : (float)((cbp[OFF_CB + t] >> (d - 1)) & 1);
          float gs = (d == 0) ? pp_s[t] * ws[OFF_SUMS + t * SUMS_STRIDE + 2 + h]
                              : ws[OFF_SUMS + t * SUMS_STRIDE + 10 + h * 21 + (d - 1)];
          val += sk_s[t][h] * xk - gs * s0i_s[t];
        }
      } else if (o < 218) { int h = o - 214;
        for (int t = NSTEP2; t < NSTEPS; t++) val += sk_s[t][h] - ws[OFF_SUMS + t * SUMS_STRIDE + 2 + h] * s0i_s[t];
      } else if (o < 222) { int h = o - 218;
        for (int t = NSTEP2; t < NSTEPS; t++) val += hk_s[t][h] - ws[OFF_SUMS + t * SUMS_STRIDE + 6 + h] * s0i_s[t];
      } else {
        for (int t = NSTEP2; t < NSTEPS; t++) val += 1.0f - ws[OFF_SUMS + t * SUMS_STRIDE + 1] * s0i_s[t];
      }
    }
    out[o] = val;
  }
}

extern "C" void kernel_launch(void* const* d_in, const int* in_sizes, int n_in,
                              void* d_out, int out_size, void* d_ws, size_t ws_size,
                              hipStream_t stream) {
  const float* p0   = (const float*)d_in[0];
  const float* sel  = (const float*)d_in[1];
  const float* W1_2 = (const float*)d_in[2]; const float* b1_2 = (const float*)d_in[3];
  const float* W2_2 = (const float*)d_in[4]; const float* b2_2 = (const float*)d_in[5];
  const float* W1_3 = (const float*)d_in[6]; const float* b1_3 = (const float*)d_in[7];
  const float* W2_3 = (const float*)d_in[8]; const float* b2_3 = (const float*)d_in[9];
  float* out = (float*)d_out;
  float* ws  = (float*)d_ws;
  hipLaunchKernelGGL(kz, dim3(1), dim3(256), 0, stream, p0, sel, W1_2, b1_2, W1_3, b1_3, ws);
  hipLaunchKernelGGL(ka, dim3(KAOFF.total), dim3(256), 0, stream,
                     W1_2, b1_2, W2_2, b2_2, W1_3, b1_3, W2_3, b2_3, ws);
  hipLaunchKernelGGL(kb, dim3(1), dim3(64), 0, stream, p0,
                     W1_2, b1_2, W2_2, b2_2, W1_3, b1_3, W2_3, b2_3, ws, out);
  hipLaunchKernelGGL(kc, dim3(KC_BLOCKS), dim3(256), 0, stream,
                     W1_2, b1_2, W2_2, b2_2, W1_3, b1_3, W2_3, b2_3, ws);
  hipLaunchKernelGGL(kd, dim3(1), dim3(256), 0, stream,
                     W1_2, b1_2, W2_2, b2_2, W1_3, b1_3, W2_3, b2_3, ws, out);
}

// Round 8
// 176.893 us; speedup vs baseline: 1.5100x; 1.2457x over previous
//
#include <hip/hip_runtime.h>
#include <cstdint>
#include <cmath>

#define DEV __device__ __forceinline__

constexpr int SEL = 20;
constexpr int NSTEP2 = 10, NSTEP3 = 22, NSTEPS = 32;
constexpr int L2 = SEL + 1;   // 21 bits, group2
constexpr int L3 = SEL;       // 20 bits, group3
constexpr int H = 4;
constexpr int P = 6;          // Chebyshev probes (degree-5: error ~1e-7 for this flat fn)

// ---- ws layout (float indices) ----
constexpr int OFF_T      = 0;                               // T[2][22][P] = 264
constexpr int OFF_SUMS   = OFF_T + 2 * 22 * P;
constexpr int SUMS_STRIDE = 96;                             // [0]=Se [1]=Sw [2..5]=Sws [6..9]=Swh [10+h*21+d]=GW1
constexpr int OFF_PCHAIN = OFF_SUMS + NSTEPS * SUMS_STRIDE;
constexpr int OFF_KEYB   = OFF_PCHAIN + 40;                 // keybase[32][4]
constexpr int OFF_CT     = OFF_KEYB + 128;                  // int c_t[32]
constexpr int OFF_CB     = OFF_CT + 32;                     // uint chunkbits[32]
constexpr int OFF_NEED   = OFF_CB + 32;                     // uint neededmask[2]
constexpr int WS_FLOATS  = OFF_NEED + 8;

// runtime-indexed (kb)
__constant__ float CHEB_P[P] = {0.98296291315f, 0.85355339059f, 0.62940952255f,
                                0.37059047745f, 0.14644660941f, 0.01703708685f};
__constant__ float CHEB_W[P] = {0.25881904510f, -0.70710678119f, 0.96592582629f,
                                -0.96592582629f, 0.70710678119f, -0.25881904510f};
// compile-time immediates (ka)
constexpr float CHEB_PC[P] = {0.98296291315f, 0.85355339059f, 0.62940952255f,
                              0.37059047745f, 0.14644660941f, 0.01703708685f};

struct Binom { unsigned v[22][22]; };
constexpr Binom make_binom() {
  Binom b{};
  for (int n = 0; n < 22; n++) {
    b.v[n][0] = 1;
    for (int k = 1; k < 22; k++)
      b.v[n][k] = (k > n) ? 0u : (k == n ? 1u : b.v[n - 1][k - 1] + b.v[n - 1][k]);
  }
  return b;
}
constexpr Binom BN_H = make_binom();
__device__ constexpr Binom BN = make_binom();

DEV float fast_tanh(float x) {
  float e = exp2f(x * 2.8853900817779268f);  // e^(2x)
  return 1.0f - 2.0f * __builtin_amdgcn_rcpf(e + 1.0f);
}
DEV float fast_exp(float x) { return exp2f(x * 1.4426950408889634f); }

// native fp32 atomic (global_atomic_add_f32) — avoids hipcc's default CAS loop
DEV void gatomic(float* p, float v) { unsafeAtomicAdd(p, v); }

DEV unsigned gosper(unsigned cmb) {
  unsigned u = cmb & (~cmb + 1u);
  unsigned v = cmb + u;
  return v | ((cmb ^ v) >> (1 + __ffs(u)));
}

DEV unsigned unrank_lds(const unsigned* sBN, int L, int c, unsigned r) {
  unsigned cmb = 0; int kk = c;
  for (int bb = L - 1; bb >= 0 && kk > 0; bb--) {
    unsigned cnt = sBN[bb * 22 + kk];
    if (r >= cnt) { cmb |= 1u << bb; r -= cnt; kk--; }
  }
  return cmb;
}

constexpr unsigned cdiv_u(unsigned a, unsigned b) { return (a + b - 1) / b; }

DEV float wsum64(float v) {
  for (int m = 1; m < 64; m <<= 1) v += __shfl_xor(v, m);
  return v;
}

// =================== Kernel Z: init / decode chunks ===================
__global__ void kz(const float* p0, const float* sel,
                   const float* W1_2, const float* b1_2,
                   const float* W1_3, const float* b1_3, float* ws) {
  int t = threadIdx.x;
  for (int i = t; i < WS_FLOATS; i += blockDim.x) ws[i] = 0.0f;
  __syncthreads();
  if (t < NSTEPS) {
    int g = (t < NSTEP2) ? 0 : 1;
    int L = g ? L3 : L2;
    const float* sbase = sel + (g ? (NSTEP2 * L2 + (t - NSTEP2) * L3) : t * L2);
    unsigned cb = 0; int c = 0;
    for (int d = 0; d < L; d++)
      if (sbase[d] > 0.5f) { cb |= 1u << d; c++; }
    ((int*)ws)[OFF_CT + t] = c;
    ((unsigned*)ws)[OFF_CB + t] = cb;
    atomicOr(&((unsigned*)ws)[OFF_NEED + g], 1u << c);
    const float* W1 = g ? W1_3 : W1_2;
    const float* b1 = g ? b1_3 : b1_2;
    for (int h = 0; h < H; h++) {
      float s = b1[h];
      for (int d = 0; d < L; d++)
        if ((cb >> d) & 1) s += W1[h * (L + 1) + 1 + d];
      ws[OFF_KEYB + t * 4 + h] = s;
    }
    if (t == 0) ws[OFF_PCHAIN] = p0[0];
  }
}

// =================== shared helpers ===================
template<int LL>
DEV void tab_setup(const float* W1, const float* b1,
                   float4* tab0, float4* tab1, float4* tab2) {
  int tx = threadIdx.x;
  for (int i = tx; i < 384; i += 256) {
    int which = i >> 7, e = i & 127;
    int lo = which * 7; int nb = (which < 2) ? 7 : (LL - 14);
    float4 v; float* vp = (float*)&v;
    for (int h = 0; h < 4; h++) {
      float s = (which == 0) ? b1[h] : 0.0f;
      for (int j = 0; j < nb; j++)
        if ((e >> j) & 1) s += W1[h * (LL + 1) + 1 + lo + j];
      vp[h] = s;
    }
    if (which == 0) tab0[e] = v; else if (which == 1) tab1[e] = v; else tab2[e] = v;
  }
}

// =================== Kernel A: per-class tabulation of T[g][c][j] ===================
constexpr int KA_CPT = 16;
constexpr int KA_RPB = 256 * KA_CPT; // 4096 ranks per block

struct KaOff { int off2[23]; int off3[22]; int total2; int total; };
constexpr KaOff make_kaoff() {
  KaOff o{};
  int cum = 0;
  for (int c = 0; c <= 21; c++) { o.off2[c] = cum; cum += (int)cdiv_u(BN_H.v[21][c], KA_RPB); }
  o.off2[22] = cum; o.total2 = cum;
  int cum3 = 0;
  for (int c = 0; c <= 20; c++) { o.off3[c] = cum3; cum3 += (int)cdiv_u(BN_H.v[20][c], KA_RPB); }
  o.off3[21] = cum3;
  o.total = cum + cum3;
  return o;
}
constexpr KaOff KAOFF = make_kaoff();

template<int LL>
DEV void ka_work(int g, int c, int sub,
                 const float* W1, const float* b1, const float* W2, const float* b2,
                 float* ws, unsigned* sBN, float4* tab0, float4* tab1, float4* tab2,
                 float* sT) {
  int tx = threadIdx.x;
  const unsigned* bnf = &BN.v[0][0];
  for (int i = tx; i < 484; i += 256) sBN[i] = bnf[i];
  if (tx < P) sT[tx] = 0.0f;
  tab_setup<LL>(W1, b1, tab0, tab1, tab2);
  __syncthreads();
  float a0 = W1[0], a1 = W1[LL + 1], a2 = W1[2 * (LL + 1)], a3 = W1[3 * (LL + 1)];
  float w0 = W2[0], w1 = W2[1], w2 = W2[2], w3 = W2[3];
  float b2s = b2[0];
  unsigned C = BN.v[LL][c];
  unsigned r0 = (unsigned)sub * KA_RPB + (unsigned)tx * KA_CPT;
  int nI = (int)C - (int)r0;
  if (nI > KA_CPT) nI = KA_CPT;
  unsigned cmb = (nI > 0) ? unrank_lds(sBN, LL, c, r0) : 0u;
  float acc0 = 0, acc1 = 0, acc2 = 0, acc3 = 0, acc4 = 0, acc5 = 0;
#pragma unroll 1
  for (int k = 0; k < nI; k++) {
    unsigned n = cmb;
    float4 v0 = tab0[n & 127], v1 = tab1[(n >> 7) & 127], v2 = tab2[(n >> 14) & 127];
    float base0 = v0.x + v1.x + v2.x, base1 = v0.y + v1.y + v2.y;
    float base2 = v0.z + v1.z + v2.z, base3 = v0.w + v1.w + v2.w;
#define PROBE(i) { \
    float t0 = fast_tanh(fmaf(CHEB_PC[i], a0, base0)); \
    float t1 = fast_tanh(fmaf(CHEB_PC[i], a1, base1)); \
    float t2 = fast_tanh(fmaf(CHEB_PC[i], a2, base2)); \
    float t3 = fast_tanh(fmaf(CHEB_PC[i], a3, base3)); \
    float outv = b2s + w0 * t0 + w1 * t1 + w2 * t2 + w3 * t3; \
    acc##i += fast_exp(outv); }
    PROBE(0) PROBE(1) PROBE(2) PROBE(3) PROBE(4) PROBE(5)
#undef PROBE
    cmb = gosper(cmb);
  }
#define FLUSH(i) { \
    float v = wsum64(acc##i); \
    if ((tx & 63) == 0 && v != 0.0f) atomicAdd(&sT[i], v); }
  FLUSH(0) FLUSH(1) FLUSH(2) FLUSH(3) FLUSH(4) FLUSH(5)
#undef FLUSH
  __syncthreads();
  if (tx < P) {
    float v = sT[tx];
    if (v != 0.0f) gatomic(&ws[OFF_T + g * 22 * P + c * P + tx], v);
  }
}

__global__ __launch_bounds__(256) void ka(
    const float* W1_2, const float* b1_2, const float* W2_2, const float* b2_2,
    const float* W1_3, const float* b1_3, const float* W2_3, const float* b2_3,
    float* ws) {
  __shared__ unsigned sBN[484];
  __shared__ float4 tab0[128], tab1[128], tab2[128];
  __shared__ float sT[P];
  int b = blockIdx.x;
  int g, c = 0, sub;
  if (b < KAOFF.total2) {
    g = 0;
#pragma unroll
    for (int cc = 1; cc <= 21; cc++) if (b >= KAOFF.off2[cc]) c = cc;
    sub = b - KAOFF.off2[c];
  } else {
    g = 1; int b3 = b - KAOFF.total2;
#pragma unroll
    for (int cc = 1; cc <= 20; cc++) if (b3 >= KAOFF.off3[cc]) c = cc;
    sub = b3 - KAOFF.off3[c];
  }
  unsigned need = ((const unsigned*)ws)[OFF_NEED + g];
  if (!((need >> c) & 1)) return;
  if (g == 0) ka_work<21>(0, c, sub, W1_2, b1_2, W2_2, b2_2, ws, sBN, tab0, tab1, tab2, sT);
  else        ka_work<20>(1, c, sub, W1_3, b1_3, W2_3, b2_3, ws, sBN, tab0, tab1, tab2, sT);
}

// =================== Kernel B: prob chain, 64-lane cooperative ===================
__global__ __launch_bounds__(64) void kb(const float* p0in,
                   const float* W1_2, const float* b1_2, const float* W2_2, const float* b2_2,
                   const float* W1_3, const float* b1_3, const float* W2_3, const float* b2_3,
                   float* ws, float* out) {
  __shared__ float sT[2 * 22 * P];     // 264
  __shared__ float sKEYB[128], sW1c0[8], sW2[8], sB2[2];
  __shared__ int sCT[32];
  int lane = threadIdx.x;
  for (int i = lane; i < 2 * 22 * P; i += 64) sT[i] = ws[OFF_T + i];
  for (int i = lane; i < 128; i += 64) sKEYB[i] = ws[OFF_KEYB + i];
  if (lane < 32) sCT[lane] = ((const int*)ws)[OFF_CT + lane];
  if (lane < 4) {
    sW1c0[lane]     = W1_2[lane * (L2 + 1)];
    sW1c0[4 + lane] = W1_3[lane * (L3 + 1)];
    sW2[lane]     = W2_2[lane];
    sW2[4 + lane] = W2_3[lane];
  }
  if (lane == 0) { sB2[0] = b2_2[0]; sB2[1] = b2_3[0]; }
  __syncthreads();
  float p = p0in[0];
  if (lane == 0) out[0] = p;
  int h = lane & 3;
  int j = lane & 7;
#pragma unroll 1
  for (int tt = 0; tt < NSTEPS; tt++) {
    int g = (tt < NSTEP2) ? 0 : 1;
    int c = sCT[tt];
    // outk: lanes compute h-term, reduce within quad
    float hk = fast_tanh(sKEYB[tt * 4 + h] + p * sW1c0[g * 4 + h]);
    float contrib = sW2[g * 4 + h] * hk;
    contrib += __shfl_xor(contrib, 1);
    contrib += __shfl_xor(contrib, 2);
    float outk = sB2[g] + contrib;
    // barycentric interp of Se at p: lanes j<P hold node terms, reduce within octet
    float num = 0.0f, den = 0.0f;
    if (j < P) {
      float Tv = sT[(g * 22 + c) * P + j];
      float d = p - CHEB_P[j];
      float ad = fabsf(d);
      d = (ad < 1e-9f) ? ((d < 0.0f) ? -1e-9f : 1e-9f) : d;
      float q = CHEB_W[j] / d;
      num = q * Tv; den = q;
    }
    num += __shfl_xor(num, 1); den += __shfl_xor(den, 1);
    num += __shfl_xor(num, 2); den += __shfl_xor(den, 2);
    num += __shfl_xor(num, 4); den += __shfl_xor(den, 4);
    float Se = num / den;
    p = fast_exp(outk) / Se;
    if (lane == 0) { out[1 + tt] = p; ws[OFF_PCHAIN + 1 + tt] = p; }
  }
}

// =================== Kernel C: exact per-class 94-sum reductions, SINGLE pass ===================
constexpr int KC_CPT = 16;
constexpr int KC_RPB = 256 * KC_CPT; // 4096
constexpr int KC_B2 = (int)cdiv_u(BN_H.v[21][10], KC_RPB); // 87
constexpr int KC_B3 = (int)cdiv_u(BN_H.v[20][10], KC_RPB); // 46
constexpr int KC_BLOCKS = NSTEP2 * KC_B2 + NSTEP3 * KC_B3;

template<int LL>
DEV void kc_work(int t, int sub,
                 const float* W1, const float* b1, const float* W2, const float* b2,
                 float* ws, unsigned* sBN, float4* tab0, float4* tab1, float4* tab2,
                 float* sS) {
  int tx = threadIdx.x;
  int c = ((const int*)ws)[OFF_CT + t];
  unsigned C = BN.v[LL][c];
  unsigned rank0 = (unsigned)sub * KC_RPB;
  if (rank0 >= C) return;   // block-uniform early exit (before any barrier)
  const unsigned* bnf = &BN.v[0][0];
  for (int i = tx; i < 484; i += 256) sBN[i] = bnf[i];
  if (tx < SUMS_STRIDE) sS[tx] = 0.0f;
  tab_setup<LL>(W1, b1, tab0, tab1, tab2);
  __syncthreads();
  float p = ws[OFF_PCHAIN + t];
  float pa0 = p * W1[0], pa1 = p * W1[LL + 1], pa2 = p * W1[2 * (LL + 1)], pa3 = p * W1[3 * (LL + 1)];
  float w0 = W2[0], w1 = W2[1], w2 = W2[2], w3 = W2[3];
  float b2s = b2[0];
  unsigned r0 = rank0 + (unsigned)tx * KC_CPT;
  int nI = (int)C - (int)r0;
  if (nI > KC_CPT) nI = KC_CPT;
  unsigned cmb = (nI > 0) ? unrank_lds(sBN, LL, c, r0) : 0u;

  float aE = 0, aW = 0, aQ0 = 0, aQ1 = 0, aQ2 = 0, aQ3 = 0;
  float aWH0 = 0, aWH1 = 0, aWH2 = 0, aWH3 = 0;
#define AG_DECL(d) float g##d##_0 = 0, g##d##_1 = 0, g##d##_2 = 0, g##d##_3 = 0;
  AG_DECL(0) AG_DECL(1) AG_DECL(2) AG_DECL(3) AG_DECL(4) AG_DECL(5) AG_DECL(6)
  AG_DECL(7) AG_DECL(8) AG_DECL(9) AG_DECL(10) AG_DECL(11) AG_DECL(12) AG_DECL(13)
  AG_DECL(14) AG_DECL(15) AG_DECL(16) AG_DECL(17) AG_DECL(18) AG_DECL(19) AG_DECL(20)
#undef AG_DECL

#pragma unroll 1
  for (int k = 0; k < nI; k++) {
    unsigned n = cmb;
    float4 v0 = tab0[n & 127], v1 = tab1[(n >> 7) & 127], v2 = tab2[(n >> 14) & 127];
    float t0 = fast_tanh(v0.x + v1.x + v2.x + pa0);
    float t1 = fast_tanh(v0.y + v1.y + v2.y + pa1);
    float t2 = fast_tanh(v0.z + v1.z + v2.z + pa2);
    float t3 = fast_tanh(v0.w + v1.w + v2.w + pa3);
    float outv = b2s + w0 * t0 + w1 * t1 + w2 * t2 + w3 * t3;
    float q0 = outv * (1.0f - t0 * t0) * w0;
    float q1 = outv * (1.0f - t1 * t1) * w1;
    float q2 = outv * (1.0f - t2 * t2) * w2;
    float q3 = outv * (1.0f - t3 * t3) * w3;
    aE += fast_exp(outv); aW += outv;
    aQ0 += q0; aQ1 += q1; aQ2 += q2; aQ3 += q3;
    aWH0 = fmaf(outv, t0, aWH0); aWH1 = fmaf(outv, t1, aWH1);
    aWH2 = fmaf(outv, t2, aWH2); aWH3 = fmaf(outv, t3, aWH3);
#define GU(d) { float bd = (float)((n >> d) & 1u); \
    g##d##_0 = fmaf(bd, q0, g##d##_0); g##d##_1 = fmaf(bd, q1, g##d##_1); \
    g##d##_2 = fmaf(bd, q2, g##d##_2); g##d##_3 = fmaf(bd, q3, g##d##_3); }
    GU(0) GU(1) GU(2) GU(3) GU(4) GU(5) GU(6) GU(7) GU(8) GU(9)
    GU(10) GU(11) GU(12) GU(13) GU(14) GU(15) GU(16) GU(17) GU(18) GU(19)
    if constexpr (LL == 21) { GU(20) }
#undef GU
    cmb = gosper(cmb);
  }

  int lane = tx & 63;
  float r;
  r = wsum64(aE);   if (lane == 0 && r != 0.0f) atomicAdd(&sS[0], r);
  r = wsum64(aW);   if (lane == 0 && r != 0.0f) atomicAdd(&sS[1], r);
  r = wsum64(aQ0);  if (lane == 0 && r != 0.0f) atomicAdd(&sS[2], r);
  r = wsum64(aQ1);  if (lane == 0 && r != 0.0f) atomicAdd(&sS[3], r);
  r = wsum64(aQ2);  if (lane == 0 && r != 0.0f) atomicAdd(&sS[4], r);
  r = wsum64(aQ3);  if (lane == 0 && r != 0.0f) atomicAdd(&sS[5], r);
  r = wsum64(aWH0); if (lane == 0 && r != 0.0f) atomicAdd(&sS[6], r);
  r = wsum64(aWH1); if (lane == 0 && r != 0.0f) atomicAdd(&sS[7], r);
  r = wsum64(aWH2); if (lane == 0 && r != 0.0f) atomicAdd(&sS[8], r);
  r = wsum64(aWH3); if (lane == 0 && r != 0.0f) atomicAdd(&sS[9], r);
#define GF(d) { \
    r = wsum64(g##d##_0); if (lane == 0 && r != 0.0f) atomicAdd(&sS[10 + 0 * 21 + d], r); \
    r = wsum64(g##d##_1); if (lane == 0 && r != 0.0f) atomicAdd(&sS[10 + 1 * 21 + d], r); \
    r = wsum64(g##d##_2); if (lane == 0 && r != 0.0f) atomicAdd(&sS[10 + 2 * 21 + d], r); \
    r = wsum64(g##d##_3); if (lane == 0 && r != 0.0f) atomicAdd(&sS[10 + 3 * 21 + d], r); }
  GF(0) GF(1) GF(2) GF(3) GF(4) GF(5) GF(6) GF(7) GF(8) GF(9)
  GF(10) GF(11) GF(12) GF(13) GF(14) GF(15) GF(16) GF(17) GF(18) GF(19)
  if constexpr (LL == 21) { GF(20) }
#undef GF
  __syncthreads();
  if (tx < SUMS_STRIDE) {
    float v = sS[tx];
    if (v != 0.0f) gatomic(&ws[OFF_SUMS + t * SUMS_STRIDE + tx], v);
  }
}

__global__ __launch_bounds__(256) void kc(
    const float* W1_2, const float* b1_2, const float* W2_2, const float* b2_2,
    const float* W1_3, const float* b1_3, const float* W2_3, const float* b2_3,
    float* ws) {
  __shared__ unsigned sBN[484];
  __shared__ float4 tab0[128], tab1[128], tab2[128];
  __shared__ float sS[SUMS_STRIDE];
  int b = blockIdx.x;
  if (b < NSTEP2 * KC_B2) {
    int t = b / KC_B2, sub = b % KC_B2;
    kc_work<21>(t, sub, W1_2, b1_2, W2_2, b2_2, ws, sBN, tab0, tab1, tab2, sS);
  } else {
    int bb = b - NSTEP2 * KC_B2;
    int t = NSTEP2 + bb / KC_B3, sub = bb % KC_B3;
    kc_work<20>(t, sub, W1_3, b1_3, W2_3, b2_3, ws, sBN, tab0, tab1, tab2, sS);
  }
}

// =================== Kernel D: finalize gradient outputs ===================
__global__ __launch_bounds__(256) void kd(
                   const float* W1_2, const float* b1_2, const float* W2_2, const float* b2_2,
                   const float* W1_3, const float* b1_3, const float* W2_3, const float* b2_3,
                   const float* ws, float* out) {
  __shared__ float sS[NSTEPS * SUMS_STRIDE];   // 12 KB
  __shared__ float sk_s[NSTEPS][4], hk_s[NSTEPS][4], pp_s[NSTEPS], s0i_s[NSTEPS];
  int tx = threadIdx.x;
  for (int i = tx; i < NSTEPS * SUMS_STRIDE; i += 256) sS[i] = ws[OFF_SUMS + i];
  __syncthreads();
  if (tx < NSTEPS) {
    int t = tx; int g = (t < NSTEP2) ? 0 : 1; int L = g ? L3 : L2;
    const float* W1 = g ? W1_3 : W1_2;
    const float* W2 = g ? W2_3 : W2_2;
    float p = ws[OFF_PCHAIN + t];
    pp_s[t] = p;
    s0i_s[t] = 1.0f / sS[t * SUMS_STRIDE + 0];
    for (int h = 0; h < 4; h++) {
      float hk = fast_tanh(ws[OFF_KEYB + t * 4 + h] + p * W1[h * (L + 1)]);
      hk_s[t][h] = hk;
      sk_s[t][h] = (1.0f - hk * hk) * W2[h];
    }
  }
  __syncthreads();
  const unsigned* cbp = (const unsigned*)ws;
  for (int o = 33 + tx; o < 223; o += blockDim.x) {
    float val = 0.0f;
    if (o < 130) {                           // ---- group2 grads ----
      if (o < 121) {                         // W1_2 grad [4][22]
        int e = o - 33; int h = e / 22, d = e % 22;
        for (int t = 0; t < NSTEP2; t++) {
          float xk = (d == 0) ? pp_s[t] : (float)((cbp[OFF_CB + t] >> (d - 1)) & 1);
          float gs = (d == 0) ? pp_s[t] * sS[t * SUMS_STRIDE + 2 + h]
                              : sS[t * SUMS_STRIDE + 10 + h * 21 + (d - 1)];
          val += sk_s[t][h] * xk - gs * s0i_s[t];
        }
      } else if (o < 125) { int h = o - 121;
        for (int t = 0; t < NSTEP2; t++) val += sk_s[t][h] - sS[t * SUMS_STRIDE + 2 + h] * s0i_s[t];
      } else if (o < 129) { int h = o - 125;
        for (int t = 0; t < NSTEP2; t++) val += hk_s[t][h] - sS[t * SUMS_STRIDE + 6 + h] * s0i_s[t];
      } else {
        for (int t = 0; t < NSTEP2; t++) val += 1.0f - sS[t * SUMS_STRIDE + 1] * s0i_s[t];
      }
    } else {                                 // ---- group3 grads ----
      if (o < 214) {                         // W1_3 grad [4][21]
        int e = o - 130; int h = e / 21, d = e % 21;
        for (int t = NSTEP2; t < NSTEPS; t++) {
          float xk = (d == 0) ? pp_s[t] : (float)((cbp[OFF_CB + t] >> (d - 1)) & 1);
          float gs = (d == 0) ? pp_s[t] * sS[t * SUMS_STRIDE + 2 + h]
                              : sS[t * SUMS_STRIDE + 10 + h * 21 + (d - 1)];
          val += sk_s[t][h] * xk - gs * s0i_s[t];
        }
      } else if (o < 218) { int h = o - 214;
        for (int t = NSTEP2; t < NSTEPS; t++) val += sk_s[t][h] - sS[t * SUMS_STRIDE + 2 + h] * s0i_s[t];
      } else if (o < 222) { int h = o - 218;
        for (int t = NSTEP2; t < NSTEPS; t++) val += hk_s[t][h] - sS[t * SUMS_STRIDE + 6 + h] * s0i_s[t];
      } else {
        for (int t = NSTEP2; t < NSTEPS; t++) val += 1.0f - sS[t * SUMS_STRIDE + 1] * s0i_s[t];
      }
    }
    out[o] = val;
  }
}

extern "C" void kernel_launch(void* const* d_in, const int* in_sizes, int n_in,
                              void* d_out, int out_size, void* d_ws, size_t ws_size,
                              hipStream_t stream) {
  const float* p0   = (const float*)d_in[0];
  const float* sel  = (const float*)d_in[1];
  const float* W1_2 = (const float*)d_in[2]; const float* b1_2 = (const float*)d_in[3];
  const float* W2_2 = (const float*)d_in[4]; const float* b2_2 = (const float*)d_in[5];
  const float* W1_3 = (const float*)d_in[6]; const float* b1_3 = (const float*)d_in[7];
  const float* W2_3 = (const float*)d_in[8]; const float* b2_3 = (const float*)d_in[9];
  float* out = (float*)d_out;
  float* ws  = (float*)d_ws;
  hipLaunchKernelGGL(kz, dim3(1), dim3(256), 0, stream, p0, sel, W1_2, b1_2, W1_3, b1_3, ws);
  hipLaunchKernelGGL(ka, dim3(KAOFF.total), dim3(256), 0, stream,
                     W1_2, b1_2, W2_2, b2_2, W1_3, b1_3, W2_3, b2_3, ws);
  hipLaunchKernelGGL(kb, dim3(1), dim3(64), 0, stream, p0,
                     W1_2, b1_2, W2_2, b2_2, W1_3, b1_3, W2_3, b2_3, ws, out);
  hipLaunchKernelGGL(kc, dim3(KC_BLOCKS), dim3(256), 0, stream,
                     W1_2, b1_2, W2_2, b2_2, W1_3, b1_3, W2_3, b2_3, ws);
  hipLaunchKernelGGL(kd, dim3(1), dim3(256), 0, stream,
                     W1_2, b1_2, W2_2, b2_2, W1_3, b1_3, W2_3, b2_3, ws, out);
}

// Round 9
// 128.679 us; speedup vs baseline: 2.0757x; 1.3747x over previous
//
#include <hip/hip_runtime.h>
#include <cstdint>
#include <cmath>

#define DEV __device__ __forceinline__

constexpr int SEL = 20;
constexpr int NSTEP2 = 10, NSTEP3 = 22, NSTEPS = 32;
constexpr int L2 = SEL + 1;   // 21 bits, group2
constexpr int L3 = SEL;       // 20 bits, group3
constexpr int H = 4;
constexpr int P = 4;          // Chebyshev probes (deg-3: err ~1e-5 for this near-exp fn)

typedef float v2f __attribute__((ext_vector_type(2)));

// ---- ws layout (float indices) ----
constexpr int OFF_T      = 0;                               // T[2][22][P] = 176
constexpr int OFF_SUMS   = OFF_T + 2 * 22 * P;
constexpr int SUMS_STRIDE = 96;                             // [0]=Se [1]=Sw [2..5]=Sws [6..9]=Swh [10+h*21+d]=GW1
constexpr int OFF_PCHAIN = OFF_SUMS + NSTEPS * SUMS_STRIDE;
constexpr int OFF_KEYB   = OFF_PCHAIN + 40;                 // keybase[32][4]
constexpr int OFF_CT     = OFF_KEYB + 128;                  // int c_t[32]
constexpr int OFF_CB     = OFF_CT + 32;                     // uint chunkbits[32]
constexpr int OFF_NEED   = OFF_CB + 32;                     // uint neededmask[2]
constexpr int WS_FLOATS  = OFF_NEED + 8;

constexpr float K2E = 2.8853900817779268f;   // 2*log2(e)
constexpr float KE  = 1.4426950408889634f;   // log2(e)

// runtime-indexed (kb)
__constant__ float CHEB_P[P] = {0.96193976625f, 0.69134171618f, 0.30865828382f, 0.03806023375f};
__constant__ float CHEB_W[P] = {0.38268343236f, -0.92387953251f, 0.92387953251f, -0.38268343236f};
// compile-time immediates (ka)
constexpr float CHEB_PC[P] = {0.96193976625f, 0.69134171618f, 0.30865828382f, 0.03806023375f};

struct Binom { unsigned v[22][22]; };
constexpr Binom make_binom() {
  Binom b{};
  for (int n = 0; n < 22; n++) {
    b.v[n][0] = 1;
    for (int k = 1; k < 22; k++)
      b.v[n][k] = (k > n) ? 0u : (k == n ? 1u : b.v[n - 1][k - 1] + b.v[n - 1][k]);
  }
  return b;
}
constexpr Binom BN_H = make_binom();
__device__ constexpr Binom BN = make_binom();

DEV float fast_tanh(float x) {
  float e = exp2f(x * K2E);  // e^(2x)
  return 1.0f - 2.0f * __builtin_amdgcn_rcpf(e + 1.0f);
}
DEV float fast_exp(float x) { return exp2f(x * KE); }

// native fp32 atomic (global_atomic_add_f32) — avoids hipcc's default CAS loop
DEV void gatomic(float* p, float v) { unsafeAtomicAdd(p, v); }

DEV unsigned gosper(unsigned cmb) {
  unsigned u = cmb & (~cmb + 1u);
  unsigned v = cmb + u;
  return v | ((cmb ^ v) >> (1 + __ffs(u)));
}

DEV unsigned unrank_lds(const unsigned* sBN, int L, int c, unsigned r) {
  unsigned cmb = 0; int kk = c;
  for (int bb = L - 1; bb >= 0 && kk > 0; bb--) {
    unsigned cnt = sBN[bb * 22 + kk];
    if (r >= cnt) { cmb |= 1u << bb; r -= cnt; kk--; }
  }
  return cmb;
}

constexpr unsigned cdiv_u(unsigned a, unsigned b) { return (a + b - 1) / b; }

DEV float wsum64(float v) {
  for (int m = 1; m < 64; m <<= 1) v += __shfl_xor(v, m);
  return v;
}

// tab setup: 3 x 128-entry tables of per-7-bit-group partial sums (which==0 holds b1 [+ p*W1col0])
template<int LL>
DEV void tab_setup(const float* W1, const float* b1, float p,
                   float4* tab0, float4* tab1, float4* tab2) {
  int tx = threadIdx.x;
  for (int i = tx; i < 384; i += 256) {
    int which = i >> 7, e = i & 127;
    int lo = which * 7; int nb = (which < 2) ? 7 : (LL - 14);
    float4 v; float* vp = (float*)&v;
    for (int h = 0; h < 4; h++) {
      float s = (which == 0) ? (b1[h] + p * W1[h * (LL + 1)]) : 0.0f;
      for (int j = 0; j < nb; j++)
        if ((e >> j) & 1) s += W1[h * (LL + 1) + 1 + lo + j];
      vp[h] = s;
    }
    if (which == 0) tab0[e] = v; else if (which == 1) tab1[e] = v; else tab2[e] = v;
  }
}

// =================== Kernel Z: init / decode chunks ===================
__global__ void kz(const float* p0, const float* sel,
                   const float* W1_2, const float* b1_2,
                   const float* W1_3, const float* b1_3, float* ws) {
  int t = threadIdx.x;
  for (int i = t; i < WS_FLOATS; i += blockDim.x) ws[i] = 0.0f;
  __syncthreads();
  if (t < NSTEPS) {
    int g = (t < NSTEP2) ? 0 : 1;
    int L = g ? L3 : L2;
    const float* sbase = sel + (g ? (NSTEP2 * L2 + (t - NSTEP2) * L3) : t * L2);
    unsigned cb = 0; int c = 0;
    for (int d = 0; d < L; d++)
      if (sbase[d] > 0.5f) { cb |= 1u << d; c++; }
    ((int*)ws)[OFF_CT + t] = c;
    ((unsigned*)ws)[OFF_CB + t] = cb;
    atomicOr(&((unsigned*)ws)[OFF_NEED + g], 1u << c);
    const float* W1 = g ? W1_3 : W1_2;
    const float* b1 = g ? b1_3 : b1_2;
    for (int h = 0; h < H; h++) {
      float s = b1[h];
      for (int d = 0; d < L; d++)
        if ((cb >> d) & 1) s += W1[h * (L + 1) + 1 + d];
      ws[OFF_KEYB + t * 4 + h] = s;
    }
    if (t == 0) ws[OFF_PCHAIN] = p0[0];
  }
}

// =================== Kernel A: per-class tabulation of T[g][c][j], E-trick ===================
constexpr int KA_CPT = 16;
constexpr int KA_RPB = 256 * KA_CPT; // 4096

struct KaOff { int off2[23]; int off3[22]; int total2; int total; };
constexpr KaOff make_kaoff() {
  KaOff o{};
  int cum = 0;
  for (int c = 0; c <= 21; c++) { o.off2[c] = cum; cum += (int)cdiv_u(BN_H.v[21][c], KA_RPB); }
  o.off2[22] = cum; o.total2 = cum;
  int cum3 = 0;
  for (int c = 0; c <= 20; c++) { o.off3[c] = cum3; cum3 += (int)cdiv_u(BN_H.v[20][c], KA_RPB); }
  o.off3[21] = cum3;
  o.total = cum + cum3;
  return o;
}
constexpr KaOff KAOFF = make_kaoff();

template<int LL>
DEV void ka_work(int g, int c, int sub,
                 const float* W1, const float* b1, const float* W2, const float* b2,
                 float* ws, unsigned* sBN, float4* tab0, float4* tab1, float4* tab2,
                 float* sT) {
  int tx = threadIdx.x;
  const unsigned* bnf = &BN.v[0][0];
  for (int i = tx; i < 484; i += 256) sBN[i] = bnf[i];
  if (tx < P) sT[tx] = 0.0f;
  tab_setup<LL>(W1, b1, 0.0f, tab0, tab1, tab2);
  __syncthreads();
  float a0 = W1[0], a1 = W1[LL + 1], a2 = W1[2 * (LL + 1)], a3 = W1[3 * (LL + 1)];
  float w0 = W2[0], w1 = W2[1], w2 = W2[2], w3 = W2[3];
  float W0 = b2[0] + w0 + w1 + w2 + w3;
  float m0 = -2.0f * w0, m1 = -2.0f * w1, m2 = -2.0f * w2, m3 = -2.0f * w3;
  // A[j][h] = e^{2 p_j a_h}
#define A_DECL(j) \
  const float A##j##_0 = exp2f(K2E * CHEB_PC[j] * a0), A##j##_1 = exp2f(K2E * CHEB_PC[j] * a1), \
              A##j##_2 = exp2f(K2E * CHEB_PC[j] * a2), A##j##_3 = exp2f(K2E * CHEB_PC[j] * a3); \
  float acc##j = 0.0f;
  A_DECL(0) A_DECL(1) A_DECL(2) A_DECL(3)
#undef A_DECL
  unsigned C = BN.v[LL][c];
  unsigned r0 = (unsigned)sub * KA_RPB + (unsigned)tx * KA_CPT;
  int nI = (int)C - (int)r0;
  if (nI > KA_CPT) nI = KA_CPT;
  unsigned cmb = (nI > 0) ? unrank_lds(sBN, LL, c, r0) : 0u;
#pragma unroll 1
  for (int k = 0; k < nI; k++) {
    unsigned n = cmb;
    float4 v0 = tab0[n & 127], v1 = tab1[(n >> 7) & 127], v2 = tab2[(n >> 14) & 127];
    float E0 = exp2f(K2E * (v0.x + v1.x + v2.x));
    float E1 = exp2f(K2E * (v0.y + v1.y + v2.y));
    float E2 = exp2f(K2E * (v0.z + v1.z + v2.z));
    float E3 = exp2f(K2E * (v0.w + v1.w + v2.w));
#define PROBE(j) { \
    float o = W0 + m0 * __builtin_amdgcn_rcpf(fmaf(E0, A##j##_0, 1.0f)) \
                 + m1 * __builtin_amdgcn_rcpf(fmaf(E1, A##j##_1, 1.0f)) \
                 + m2 * __builtin_amdgcn_rcpf(fmaf(E2, A##j##_2, 1.0f)) \
                 + m3 * __builtin_amdgcn_rcpf(fmaf(E3, A##j##_3, 1.0f)); \
    acc##j += exp2f(KE * o); }
    PROBE(0) PROBE(1) PROBE(2) PROBE(3)
#undef PROBE
    cmb = gosper(cmb);
  }
#define FLUSH(j) { \
    float v = wsum64(acc##j); \
    if ((tx & 63) == 0 && v != 0.0f) atomicAdd(&sT[j], v); }
  FLUSH(0) FLUSH(1) FLUSH(2) FLUSH(3)
#undef FLUSH
  __syncthreads();
  if (tx < P) {
    float v = sT[tx];
    if (v != 0.0f) gatomic(&ws[OFF_T + g * 22 * P + c * P + tx], v);
  }
}

__global__ __launch_bounds__(256) void ka(
    const float* W1_2, const float* b1_2, const float* W2_2, const float* b2_2,
    const float* W1_3, const float* b1_3, const float* W2_3, const float* b2_3,
    float* ws) {
  __shared__ unsigned sBN[484];
  __shared__ float4 tab0[128], tab1[128], tab2[128];
  __shared__ float sT[P];
  int b = blockIdx.x;
  int g, c = 0, sub;
  if (b < KAOFF.total2) {
    g = 0;
#pragma unroll
    for (int cc = 1; cc <= 21; cc++) if (b >= KAOFF.off2[cc]) c = cc;
    sub = b - KAOFF.off2[c];
  } else {
    g = 1; int b3 = b - KAOFF.total2;
#pragma unroll
    for (int cc = 1; cc <= 20; cc++) if (b3 >= KAOFF.off3[cc]) c = cc;
    sub = b3 - KAOFF.off3[c];
  }
  unsigned need = ((const unsigned*)ws)[OFF_NEED + g];
  if (!((need >> c) & 1)) return;
  if (g == 0) ka_work<21>(0, c, sub, W1_2, b1_2, W2_2, b2_2, ws, sBN, tab0, tab1, tab2, sT);
  else        ka_work<20>(1, c, sub, W1_3, b1_3, W2_3, b2_3, ws, sBN, tab0, tab1, tab2, sT);
}

// =================== Kernel B: prob chain, 64-lane cooperative ===================
__global__ __launch_bounds__(64) void kb(const float* p0in,
                   const float* W1_2, const float* b1_2, const float* W2_2, const float* b2_2,
                   const float* W1_3, const float* b1_3, const float* W2_3, const float* b2_3,
                   float* ws, float* out) {
  __shared__ float sT[2 * 22 * P];
  __shared__ float sKEYB[128], sW1c0[8], sW2[8], sB2[2];
  __shared__ int sCT[32];
  int lane = threadIdx.x;
  for (int i = lane; i < 2 * 22 * P; i += 64) sT[i] = ws[OFF_T + i];
  for (int i = lane; i < 128; i += 64) sKEYB[i] = ws[OFF_KEYB + i];
  if (lane < 32) sCT[lane] = ((const int*)ws)[OFF_CT + lane];
  if (lane < 4) {
    sW1c0[lane]     = W1_2[lane * (L2 + 1)];
    sW1c0[4 + lane] = W1_3[lane * (L3 + 1)];
    sW2[lane]     = W2_2[lane];
    sW2[4 + lane] = W2_3[lane];
  }
  if (lane == 0) { sB2[0] = b2_2[0]; sB2[1] = b2_3[0]; }
  __syncthreads();
  float p = p0in[0];
  if (lane == 0) out[0] = p;
  int h = lane & 3;   // also the interp node index j
#pragma unroll 1
  for (int tt = 0; tt < NSTEPS; tt++) {
    int g = (tt < NSTEP2) ? 0 : 1;
    int c = sCT[tt];
    // outk: lanes compute h-term, reduce within quad
    float hk = fast_tanh(sKEYB[tt * 4 + h] + p * sW1c0[g * 4 + h]);
    float contrib = sW2[g * 4 + h] * hk;
    contrib += __shfl_xor(contrib, 1);
    contrib += __shfl_xor(contrib, 2);
    float outk = sB2[g] + contrib;
    // barycentric interp of Se at p over 4 nodes (same quad)
    float Tv = sT[(g * 22 + c) * P + h];
    float d = p - CHEB_P[h];
    float ad = fabsf(d);
    d = (ad < 1e-9f) ? ((d < 0.0f) ? -1e-9f : 1e-9f) : d;
    float q = CHEB_W[h] / d;
    float num = q * Tv, den = q;
    num += __shfl_xor(num, 1); den += __shfl_xor(den, 1);
    num += __shfl_xor(num, 2); den += __shfl_xor(den, 2);
    float Se = num / den;
    p = fast_exp(outk) / Se;
    if (lane == 0) { out[1 + tt] = p; ws[OFF_PCHAIN + 1 + tt] = p; }
  }
}

// =================== Kernel C: structured enumeration, grads via bit decomposition ===================
// combo bits: [0:5]=lane, [6:7]=wid, [8:12]=sub(5), [13:..]=i (8 bits for L=21, 7 for L=20)
constexpr int KC_BPS = 32;                   // blocks per step (both groups)
constexpr int KC_BLOCKS = NSTEPS * KC_BPS;   // 1024

template<int LL>
DEV void kc_work(int t, int sub,
                 const float* W1, const float* b1, const float* W2, const float* b2,
                 float* ws, float4* tab0, float4* tab1, float4* tab2, float* sS) {
  constexpr int NI = LL - 13;   // 8 or 7
  int tx = threadIdx.x;
  int c = ((const int*)ws)[OFF_CT + t];
  float p = ws[OFF_PCHAIN + t];
  tab_setup<LL>(W1, b1, p, tab0, tab1, tab2);   // pa folded into tab0
  if (tx < SUMS_STRIDE) sS[tx] = 0.0f;
  __syncthreads();
  int lane = tx & 63, wid = tx >> 6;
  unsigned nlow = (unsigned)lane | ((unsigned)wid << 6) | ((unsigned)sub << 8);
  int c_hi = c - __popc(nlow);
  int trip = (c_hi >= 0 && c_hi <= NI) ? (int)BN.v[NI][c_hi] : 0;
  float w0 = W2[0], w1 = W2[1], w2 = W2[2], w3 = W2[3];
  float b2s = b2[0];
  // hoisted tab reads: tab0 idx fixed; tab1 idx has only i&1 varying
  float4 v0 = tab0[nlow & 127];
  unsigned b1i = nlow >> 7;                  // 6 bits
  float4 B0 = tab1[b1i], B1 = tab1[b1i | 64];
  B0.x += v0.x; B0.y += v0.y; B0.z += v0.z; B0.w += v0.w;
  B1.x += v0.x; B1.y += v0.y; B1.z += v0.z; B1.w += v0.w;

  float aE = 0.0f, aW = 0.0f;
  v2f aQa = {0, 0}, aQb = {0, 0}, aWHa = {0, 0}, aWHb = {0, 0};
#define G_DECL(k) v2f g##k##a = {0, 0}, g##k##b = {0, 0};
  G_DECL(0) G_DECL(1) G_DECL(2) G_DECL(3) G_DECL(4) G_DECL(5) G_DECL(6) G_DECL(7)
#undef G_DECL

  unsigned iv = (trip > 0) ? ((1u << c_hi) - 1u) : 0u;
#pragma unroll 1
  for (int k = 0; k < trip; k++) {
    float4 vB = (iv & 1) ? B1 : B0;
    float4 v2 = tab2[iv >> 1];
    float t0 = fast_tanh(vB.x + v2.x);
    float t1 = fast_tanh(vB.y + v2.y);
    float t2 = fast_tanh(vB.z + v2.z);
    float t3 = fast_tanh(vB.w + v2.w);
    float outv = b2s + w0 * t0 + w1 * t1 + w2 * t2 + w3 * t3;
    float e = fast_exp(outv);
    float q0 = outv * (1.0f - t0 * t0) * w0;
    float q1 = outv * (1.0f - t1 * t1) * w1;
    float q2 = outv * (1.0f - t2 * t2) * w2;
    float q3 = outv * (1.0f - t3 * t3) * w3;
    v2f qa = {q0, q1}, qb = {q2, q3};
    aE += e; aW += outv;
    aQa += qa; aQb += qb;
    v2f ov = {outv, outv};
    v2f ta = {t0, t1}, tb = {t2, t3};
    aWHa += ov * ta; aWHb += ov * tb;
#define G_UPD(k) { float bd = (float)((iv >> k) & 1u); v2f bdv = {bd, bd}; \
    g##k##a += bdv * qa; g##k##b += bdv * qb; }
    G_UPD(0) G_UPD(1) G_UPD(2) G_UPD(3) G_UPD(4) G_UPD(5) G_UPD(6)
    if constexpr (NI == 8) { G_UPD(7) }
#undef G_UPD
    iv = gosper(iv);
  }

  // ---- epilogue ----
  float r;
  float Sws0, Sws1, Sws2, Sws3;
  r = wsum64(aE);    if (lane == 0 && r != 0.0f) atomicAdd(&sS[0], r);
  r = wsum64(aW);    if (lane == 0 && r != 0.0f) atomicAdd(&sS[1], r);
  Sws0 = wsum64(aQa.x); Sws1 = wsum64(aQa.y); Sws2 = wsum64(aQb.x); Sws3 = wsum64(aQb.y);
  if (lane == 0) {
    if (Sws0 != 0.0f) atomicAdd(&sS[2], Sws0);
    if (Sws1 != 0.0f) atomicAdd(&sS[3], Sws1);
    if (Sws2 != 0.0f) atomicAdd(&sS[4], Sws2);
    if (Sws3 != 0.0f) atomicAdd(&sS[5], Sws3);
  }
  r = wsum64(aWHa.x); if (lane == 0 && r != 0.0f) atomicAdd(&sS[6], r);
  r = wsum64(aWHa.y); if (lane == 0 && r != 0.0f) atomicAdd(&sS[7], r);
  r = wsum64(aWHb.x); if (lane == 0 && r != 0.0f) atomicAdd(&sS[8], r);
  r = wsum64(aWHb.y); if (lane == 0 && r != 0.0f) atomicAdd(&sS[9], r);
  // lane bits d=0..5: masked wsums of aQ
#define MS(d) { \
    float m = (float)((lane >> d) & 1); \
    r = wsum64(m * aQa.x); if (lane == 0 && r != 0.0f) atomicAdd(&sS[10 + 0 * 21 + d], r); \
    r = wsum64(m * aQa.y); if (lane == 0 && r != 0.0f) atomicAdd(&sS[10 + 1 * 21 + d], r); \
    r = wsum64(m * aQb.x); if (lane == 0 && r != 0.0f) atomicAdd(&sS[10 + 2 * 21 + d], r); \
    r = wsum64(m * aQb.y); if (lane == 0 && r != 0.0f) atomicAdd(&sS[10 + 3 * 21 + d], r); }
  MS(0) MS(1) MS(2) MS(3) MS(4) MS(5)
#undef MS
  // wid bits d=6,7 and sub bits d=8..12: wave/block-uniform -> conditional adds of Sws
  if (lane == 0) {
    if (wid & 1) {
      if (Sws0 != 0.0f) atomicAdd(&sS[10 + 0 * 21 + 6], Sws0);
      if (Sws1 != 0.0f) atomicAdd(&sS[10 + 1 * 21 + 6], Sws1);
      if (Sws2 != 0.0f) atomicAdd(&sS[10 + 2 * 21 + 6], Sws2);
      if (Sws3 != 0.0f) atomicAdd(&sS[10 + 3 * 21 + 6], Sws3);
    }
    if (wid & 2) {
      if (Sws0 != 0.0f) atomicAdd(&sS[10 + 0 * 21 + 7], Sws0);
      if (Sws1 != 0.0f) atomicAdd(&sS[10 + 1 * 21 + 7], Sws1);
      if (Sws2 != 0.0f) atomicAdd(&sS[10 + 2 * 21 + 7], Sws2);
      if (Sws3 != 0.0f) atomicAdd(&sS[10 + 3 * 21 + 7], Sws3);
    }
    for (int sb = 0; sb < 5; sb++)
      if ((sub >> sb) & 1) {
        if (Sws0 != 0.0f) atomicAdd(&sS[10 + 0 * 21 + 8 + sb], Sws0);
        if (Sws1 != 0.0f) atomicAdd(&sS[10 + 1 * 21 + 8 + sb], Sws1);
        if (Sws2 != 0.0f) atomicAdd(&sS[10 + 2 * 21 + 8 + sb], Sws2);
        if (Sws3 != 0.0f) atomicAdd(&sS[10 + 3 * 21 + 8 + sb], Sws3);
      }
  }
  // i bits d=13..13+NI-1
#define GF(k) if (k < NI) { \
    r = wsum64(g##k##a.x); if (lane == 0 && r != 0.0f) atomicAdd(&sS[10 + 0 * 21 + 13 + k], r); \
    r = wsum64(g##k##a.y); if (lane == 0 && r != 0.0f) atomicAdd(&sS[10 + 1 * 21 + 13 + k], r); \
    r = wsum64(g##k##b.x); if (lane == 0 && r != 0.0f) atomicAdd(&sS[10 + 2 * 21 + 13 + k], r); \
    r = wsum64(g##k##b.y); if (lane == 0 && r != 0.0f) atomicAdd(&sS[10 + 3 * 21 + 13 + k], r); }
  GF(0) GF(1) GF(2) GF(3) GF(4) GF(5) GF(6) GF(7)
#undef GF
  __syncthreads();
  if (tx < SUMS_STRIDE) {
    float v = sS[tx];
    if (v != 0.0f) gatomic(&ws[OFF_SUMS + t * SUMS_STRIDE + tx], v);
  }
}

__global__ __launch_bounds__(256) void kc(
    const float* W1_2, const float* b1_2, const float* W2_2, const float* b2_2,
    const float* W1_3, const float* b1_3, const float* W2_3, const float* b2_3,
    float* ws) {
  __shared__ float4 tab0[128], tab1[128], tab2[128];
  __shared__ float sS[SUMS_STRIDE];
  int b = blockIdx.x;
  int t = b >> 5, sub = b & 31;
  if (t < NSTEP2) kc_work<21>(t, sub, W1_2, b1_2, W2_2, b2_2, ws, tab0, tab1, tab2, sS);
  else            kc_work<20>(t, sub, W1_3, b1_3, W2_3, b2_3, ws, tab0, tab1, tab2, sS);
}

// =================== Kernel D: finalize gradient outputs ===================
__global__ __launch_bounds__(256) void kd(
                   const float* W1_2, const float* b1_2, const float* W2_2, const float* b2_2,
                   const float* W1_3, const float* b1_3, const float* W2_3, const float* b2_3,
                   const float* ws, float* out) {
  __shared__ float sS[NSTEPS * SUMS_STRIDE];   // 12 KB
  __shared__ float sk_s[NSTEPS][4], hk_s[NSTEPS][4], pp_s[NSTEPS], s0i_s[NSTEPS];
  int tx = threadIdx.x;
  for (int i = tx; i < NSTEPS * SUMS_STRIDE; i += 256) sS[i] = ws[OFF_SUMS + i];
  __syncthreads();
  if (tx < NSTEPS) {
    int t = tx; int g = (t < NSTEP2) ? 0 : 1; int L = g ? L3 : L2;
    const float* W1 = g ? W1_3 : W1_2;
    const float* W2 = g ? W2_3 : W2_2;
    float p = ws[OFF_PCHAIN + t];
    pp_s[t] = p;
    s0i_s[t] = 1.0f / sS[t * SUMS_STRIDE + 0];
    for (int h = 0; h < 4; h++) {
      float hk = fast_tanh(ws[OFF_KEYB + t * 4 + h] + p * W1[h * (L + 1)]);
      hk_s[t][h] = hk;
      sk_s[t][h] = (1.0f - hk * hk) * W2[h];
    }
  }
  __syncthreads();
  const unsigned* cbp = (const unsigned*)ws;
  for (int o = 33 + tx; o < 223; o += blockDim.x) {
    float val = 0.0f;
    if (o < 130) {                           // ---- group2 grads ----
      if (o < 121) {                         // W1_2 grad [4][22]
        int e = o - 33; int h = e / 22, d = e % 22;
        for (int t = 0; t < NSTEP2; t++) {
          float xk = (d == 0) ? pp_s[t] : (float)((cbp[OFF_CB + t] >> (d - 1)) & 1);
          float gs = (d == 0) ? pp_s[t] * sS[t * SUMS_STRIDE + 2 + h]
                              : sS[t * SUMS_STRIDE + 10 + h * 21 + (d - 1)];
          val += sk_s[t][h] * xk - gs * s0i_s[t];
        }
      } else if (o < 125) { int h = o - 121;
        for (int t = 0; t < NSTEP2; t++) val += sk_s[t][h] - sS[t * SUMS_STRIDE + 2 + h] * s0i_s[t];
      } else if (o < 129) { int h = o - 125;
        for (int t = 0; t < NSTEP2; t++) val += hk_s[t][h] - sS[t * SUMS_STRIDE + 6 + h] * s0i_s[t];
      } else {
        for (int t = 0; t < NSTEP2; t++) val += 1.0f - sS[t * SUMS_STRIDE + 1] * s0i_s[t];
      }
    } else {                                 // ---- group3 grads ----
      if (o < 214) {                         // W1_3 grad [4][21]
        int e = o - 130; int h = e / 21, d = e % 21;
        for (int t = NSTEP2; t < NSTEPS; t++) {
          float xk = (d == 0) ? pp_s[t] : (float)((cbp[OFF_CB + t] >> (d - 1)) & 1);
          float gs = (d == 0) ? pp_s[t] * sS[t * SUMS_STRIDE + 2 + h]
                              : sS[t * SUMS_STRIDE + 10 + h * 21 + (d - 1)];
          val += sk_s[t][h] * xk - gs * s0i_s[t];
        }
      } else if (o < 218) { int h = o - 214;
        for (int t = NSTEP2; t < NSTEPS; t++) val += sk_s[t][h] - sS[t * SUMS_STRIDE + 2 + h] * s0i_s[t];
      } else if (o < 222) { int h = o - 218;
        for (int t = NSTEP2; t < NSTEPS; t++) val += hk_s[t][h] - sS[t * SUMS_STRIDE + 6 + h] * s0i_s[t];
      } else {
        for (int t = NSTEP2; t < NSTEPS; t++) val += 1.0f - sS[t * SUMS_STRIDE + 1] * s0i_s[t];
      }
    }
    out[o] = val;
  }
}

extern "C" void kernel_launch(void* const* d_in, const int* in_sizes, int n_in,
                              void* d_out, int out_size, void* d_ws, size_t ws_size,
                              hipStream_t stream) {
  const float* p0   = (const float*)d_in[0];
  const float* sel  = (const float*)d_in[1];
  const float* W1_2 = (const float*)d_in[2]; const float* b1_2 = (const float*)d_in[3];
  const float* W2_2 = (const float*)d_in[4]; const float* b2_2 = (const float*)d_in[5];
  const float* W1_3 = (const float*)d_in[6]; const float* b1_3 = (const float*)d_in[7];
  const float* W2_3 = (const float*)d_in[8]; const float* b2_3 = (const float*)d_in[9];
  float* out = (float*)d_out;
  float* ws  = (float*)d_ws;
  hipLaunchKernelGGL(kz, dim3(1), dim3(256), 0, stream, p0, sel, W1_2, b1_2, W1_3, b1_3, ws);
  hipLaunchKernelGGL(ka, dim3(KAOFF.total), dim3(256), 0, stream,
                     W1_2, b1_2, W2_2, b2_2, W1_3, b1_3, W2_3, b2_3, ws);
  hipLaunchKernelGGL(kb, dim3(1), dim3(64), 0, stream, p0,
                     W1_2, b1_2, W2_2, b2_2, W1_3, b1_3, W2_3, b2_3, ws, out);
  hipLaunchKernelGGL(kc, dim3(KC_BLOCKS), dim3(256), 0, stream,
                     W1_2, b1_2, W2_2, b2_2, W1_3, b1_3, W2_3, b2_3, ws);
  hipLaunchKernelGGL(kd, dim3(1), dim3(256), 0, stream,
                     W1_2, b1_2, W2_2, b2_2, W1_3, b1_3, W2_3, b2_3, ws, out);
}